// Round 4
// baseline (6391.795 us; speedup 1.0000x reference)
//
#include <hip/hip_runtime.h>

#define B 16
#define D 256
#define T 4096
#define NQ 8
#define BINS 1024

#define OFF_C  ((size_t)B * D * T)            // quantized elems = 16777216
#define OFF_BW (OFF_C + (size_t)NQ * B * T)   // + codes 524288 -> 17301504
#define OFF_L  (OFF_BW + 1)

// A-plane LDS row stride in bytes (padded: 544 = 34*16 -> 2-way-free ds_read_b128)
#define ARS 544

typedef __attribute__((ext_vector_type(8))) short short8v;
typedef __attribute__((ext_vector_type(4))) float float4v;

__device__ __forceinline__ unsigned short f2bf(float f) {
    unsigned u = __float_as_uint(f);
    unsigned r = (u + 0x7fffu + ((u >> 16) & 1u)) >> 16;   // RNE
    return (unsigned short)r;
}
__device__ __forceinline__ float bf2f(unsigned short h) {
    return __uint_as_float(((unsigned)h) << 16);
}

// ---------------- codebook norms: f64 (exact fallback) + f32 (scan) ----------------
__global__ __launch_bounds__(256) void cbnorm_kernel(const float* __restrict__ cb,
                                                     double* __restrict__ cbn,
                                                     float* __restrict__ cbnf)
{
    const int wave = threadIdx.x >> 6;
    const int lane = threadIdx.x & 63;
    const int bin = blockIdx.x * 4 + wave;          // 0..8191 (q*1024+k)
    const float4 v = *(const float4*)&cb[(size_t)bin * D + lane * 4];
    double a = (double)v.x * v.x + (double)v.y * v.y
             + (double)v.z * v.z + (double)v.w * v.w;
    #pragma unroll
    for (int off = 32; off >= 1; off >>= 1)
        a += __shfl_xor(a, off, 64);
    if (lane == 0) { cbn[bin] = a; cbnf[bin] = (float)a; }
}

// ---------------- prep: codebook -> bf16 hi/lo planes in MFMA-B-fragment order ----
// frag c = q*512 + ntg*8 + ks ; lane l, j -> B[k=ks*32+(l>>4)*8+j][n=ntg*16+(l&15)]
__global__ __launch_bounds__(256) void prep_bfrag(const float* __restrict__ cb,
                                                  unsigned short* __restrict__ bfh,
                                                  unsigned short* __restrict__ bfl)
{
    const int c = blockIdx.x * 4 + (threadIdx.x >> 6);   // 0..4095
    const int lane = threadIdx.x & 63;
    const int q = c >> 9, ntg = (c >> 3) & 63, ks = c & 7;
    const float* src = cb + ((size_t)q * BINS + ntg * 16 + (lane & 15)) * D
                         + ks * 32 + (lane >> 4) * 8;
    short8v h, l;
    #pragma unroll
    for (int j = 0; j < 8; ++j) {
        const float v = src[j];
        const unsigned short hh = f2bf(v);
        h[j] = (short)hh;
        l[j] = (short)f2bf(v - bf2f(hh));
    }
    const size_t off = ((size_t)c * 64 + lane) * 8;
    *(short8v*)(bfh + off) = h;
    *(short8v*)(bfl + off) = l;
}

// ---------------- per-stage scan+update kernel (one launch per q) ----------------
// 64 tokens/block, 4 waves; wave w scans bins [w*256, w*256+256).
// LDS layout (bytes):
//  0     : union { A_hi[64][ARS] @0, A_lo @34816 (=69632) | resf f32[64][257]=65792 }
//  69632 : norms f32[1024]                       -> 73728
//  73728 : mg1 f32[256]; 74752: mg2; 75776: mgi  -> 76800
//  76800 : idxsL int[64]; 77056: flagsL int[64]  -> 77312
//  77312 : fbres f32[256]                        -> 78336
//  78336 : redv double[256]; 80384: redi int[256]-> 81408  (2 blocks/CU: 162816<=163840)
__global__ __launch_bounds__(256, 2) void rvq_scan(
    const float* __restrict__ rsrc, float* __restrict__ rdst,
    const float* __restrict__ cb,
    const double* __restrict__ cbn, const float* __restrict__ cbnf,
    const unsigned short* __restrict__ bfh, const unsigned short* __restrict__ bfl,
    float* __restrict__ out, double* __restrict__ lpart, int q)
{
    __shared__ __align__(16) char smem[81408];
    char*   smc   = smem;
    float*  resf  = (float*)smem;
    float*  norms = (float*)(smem + 69632);
    float*  mg1   = (float*)(smem + 73728);
    float*  mg2   = (float*)(smem + 74752);
    int*    mgi   = (int*)(smem + 75776);
    int*    idxsL = (int*)(smem + 76800);
    int*    flagsL= (int*)(smem + 77056);
    float*  fbres = (float*)(smem + 77312);
    double* redv  = (double*)(smem + 78336);
    int*    redi  = (int*)(smem + 80384);

    const int tid  = threadIdx.x;
    const int bid  = blockIdx.x;
    const int b    = bid >> 6;
    const int t0   = (bid & 63) * 64;
    const int w    = tid >> 6;
    const int lane = tid & 63;
    const int tok  = tid >> 2;          // owner token (0..63)
    const int d0   = (tid & 3) * 64;    // owner dim base

    // ---- stage residual tile global->LDS (coalesced along t), then to owner regs
    const float* rs = rsrc + (size_t)b * D * T + t0;
    float* rd = rdst + (size_t)b * D * T + t0;
    for (int it = 0; it < 64; ++it) {
        const int lin = it * 256 + tid;
        const int tk = lin & 63, d = lin >> 6;
        resf[tk * 257 + d] = rs[(size_t)d * T + tk];
    }
    __syncthreads();
    float rr[64];
    #pragma unroll
    for (int i = 0; i < 64; ++i) rr[i] = resf[tok * 257 + d0 + i];
    __syncthreads();   // before union reuse as A planes

    // ---- encode A hi/lo planes (padded rows, b128 writes)
    #pragma unroll
    for (int c = 0; c < 8; ++c) {
        short8v h, l;
        #pragma unroll
        for (int j = 0; j < 8; ++j) {
            const float v = rr[c * 8 + j];
            const unsigned short hh = f2bf(v);
            h[j] = (short)hh;
            l[j] = (short)f2bf(v - bf2f(hh));
        }
        const int byo = tok * ARS + d0 * 2 + c * 16;
        *(short8v*)(smc + byo) = h;
        *(short8v*)(smc + 34816 + byo) = l;
    }
    for (int i = tid; i < BINS; i += 256) norms[i] = cbnf[q * BINS + i];
    __syncthreads();

    // ---- distance scan via MFMA with parity double-buffered B prefetch
    float bv1[16], bv2[16]; int bi1[16];
    #pragma unroll
    for (int s = 0; s < 16; ++s) { bv1[s] = 3.4e38f; bv2[s] = 3.4e38f; bi1[s] = 0; }

    const unsigned short* ph = bfh + ((size_t)q * 512 + w * 128) * 512 + lane * 8;
    const unsigned short* pl = bfl + ((size_t)q * 512 + w * 128) * 512 + lane * 8;
    const int dbase = (lane >> 4) * 16;
    const int col   = lane & 15;
    // per-MT A row base byte offsets (hoisted)
    const int arow0 = (0 * 16 + col) * ARS;
    const int arow1 = (1 * 16 + col) * ARS;
    const int arow2 = (2 * 16 + col) * ARS;
    const int arow3 = (3 * 16 + col) * ARS;

    short8v Eh = *(const short8v*)(ph);
    short8v El = *(const short8v*)(pl);
    short8v Oh = *(const short8v*)(ph + 512);
    short8v Ol = *(const short8v*)(pl + 512);

#define KSSTEP(BH, BL, KSI, PKK) { \
    const int dby = (KSI) * 64 + dbase; \
    const short8v Ah0 = *(const short8v*)(smc + arow0 + dby); \
    const short8v Al0 = *(const short8v*)(smc + 34816 + arow0 + dby); \
    const short8v Ah1 = *(const short8v*)(smc + arow1 + dby); \
    const short8v Al1 = *(const short8v*)(smc + 34816 + arow1 + dby); \
    const short8v Ah2 = *(const short8v*)(smc + arow2 + dby); \
    const short8v Al2 = *(const short8v*)(smc + 34816 + arow2 + dby); \
    const short8v Ah3 = *(const short8v*)(smc + arow3 + dby); \
    const short8v Al3 = *(const short8v*)(smc + 34816 + arow3 + dby); \
    acc0 = __builtin_amdgcn_mfma_f32_16x16x32_bf16(Al0, BH, acc0, 0, 0, 0); \
    acc1 = __builtin_amdgcn_mfma_f32_16x16x32_bf16(Al1, BH, acc1, 0, 0, 0); \
    acc2 = __builtin_amdgcn_mfma_f32_16x16x32_bf16(Al2, BH, acc2, 0, 0, 0); \
    acc3 = __builtin_amdgcn_mfma_f32_16x16x32_bf16(Al3, BH, acc3, 0, 0, 0); \
    acc0 = __builtin_amdgcn_mfma_f32_16x16x32_bf16(Ah0, BL, acc0, 0, 0, 0); \
    acc1 = __builtin_amdgcn_mfma_f32_16x16x32_bf16(Ah1, BL, acc1, 0, 0, 0); \
    acc2 = __builtin_amdgcn_mfma_f32_16x16x32_bf16(Ah2, BL, acc2, 0, 0, 0); \
    acc3 = __builtin_amdgcn_mfma_f32_16x16x32_bf16(Ah3, BL, acc3, 0, 0, 0); \
    acc0 = __builtin_amdgcn_mfma_f32_16x16x32_bf16(Ah0, BH, acc0, 0, 0, 0); \
    acc1 = __builtin_amdgcn_mfma_f32_16x16x32_bf16(Ah1, BH, acc1, 0, 0, 0); \
    acc2 = __builtin_amdgcn_mfma_f32_16x16x32_bf16(Ah2, BH, acc2, 0, 0, 0); \
    acc3 = __builtin_amdgcn_mfma_f32_16x16x32_bf16(Ah3, BH, acc3, 0, 0, 0); \
    const int pk_ = (PKK) & 127; \
    BH = *(const short8v*)(ph + (size_t)pk_ * 512); \
    BL = *(const short8v*)(pl + (size_t)pk_ * 512); }

    #pragma unroll 1
    for (int nt = 0; nt < 16; ++nt) {
        const int kkb = nt * 8;
        float4v acc0 = {0,0,0,0}, acc1 = {0,0,0,0}, acc2 = {0,0,0,0}, acc3 = {0,0,0,0};
        KSSTEP(Eh, El, 0, kkb + 2)
        KSSTEP(Oh, Ol, 1, kkb + 3)
        KSSTEP(Eh, El, 2, kkb + 4)
        KSSTEP(Oh, Ol, 3, kkb + 5)
        KSSTEP(Eh, El, 4, kkb + 6)
        KSSTEP(Oh, Ol, 5, kkb + 7)
        KSSTEP(Eh, El, 6, kkb + 8)
        KSSTEP(Oh, Ol, 7, kkb + 9)

        const int ntg = w * 16 + nt;
        const float qn  = norms[ntg * 16 + col];
        const int   bin = ntg * 16 + col;
        #define EPI(MT, ACC) { \
            _Pragma("unroll") \
            for (int r = 0; r < 4; ++r) { \
                const float s = fmaf(-2.0f, ACC[r], qn); \
                const int sl = MT * 4 + r; \
                if (s < bv1[sl]) { bv2[sl] = bv1[sl]; bv1[sl] = s; bi1[sl] = bin; } \
                else if (s < bv2[sl]) bv2[sl] = s; } }
        EPI(0, acc0) EPI(1, acc1) EPI(2, acc2) EPI(3, acc3)
        #undef EPI
    }
#undef KSSTEP

    // ---- top-2 merge across the 16 cols, index tiebreak
    #pragma unroll
    for (int off = 1; off <= 8; off <<= 1) {
        #pragma unroll
        for (int sl = 0; sl < 16; ++sl) {
            const float ov1 = __shfl_xor(bv1[sl], off, 64);
            const float ov2 = __shfl_xor(bv2[sl], off, 64);
            const int   oi  = __shfl_xor(bi1[sl], off, 64);
            if (ov1 < bv1[sl] || (ov1 == bv1[sl] && oi < bi1[sl])) {
                bv2[sl] = fminf(bv1[sl], ov2); bv1[sl] = ov1; bi1[sl] = oi;
            } else {
                bv2[sl] = fminf(bv2[sl], ov1);
            }
        }
    }
    if ((lane & 15) == 0) {
        const int rg = lane >> 4;
        #pragma unroll
        for (int mt = 0; mt < 4; ++mt)
            #pragma unroll
            for (int r = 0; r < 4; ++r) {
                const int tk = mt * 16 + rg * 4 + r;
                const int sl = mt * 4 + r;
                mg1[tk * 4 + w] = bv1[sl];
                mg2[tk * 4 + w] = bv2[sl];
                mgi[tk * 4 + w] = bi1[sl];
            }
    }
    __syncthreads();

    if (tid < 64) {
        float g1 = mg1[tid*4], g2 = mg2[tid*4]; int gi = mgi[tid*4];
        #pragma unroll
        for (int wv = 1; wv < 4; ++wv) {
            const float v1 = mg1[tid*4+wv], v2 = mg2[tid*4+wv];
            const int   i1 = mgi[tid*4+wv];
            if (v1 < g1 || (v1 == g1 && i1 < gi)) { g2 = fminf(g1, v2); g1 = v1; gi = i1; }
            else g2 = fminf(g2, v1);
        }
        idxsL[tid]  = gi;
        flagsL[tid] = (g2 - g1 < 0.008f) ? 1 : 0;   // EPS >= 8x split-bf16 error bound
    }
    __syncthreads();

    // ---- exact f64 fallback for near ties (rare)
    const float* cbq = cb + (size_t)q * BINS * D;
    for (int tk2 = 0; tk2 < 64; ++tk2) {
        if (!flagsL[tk2]) continue;                  // uniform (LDS)
        if (tok == tk2) {
            #pragma unroll
            for (int i = 0; i < 64; ++i) fbres[d0 + i] = rr[i];
        }
        __syncthreads();
        double bb = 1e300; int bbi = 0;
        #pragma unroll
        for (int jj = 0; jj < 4; ++jj) {
            const int bin = tid + 256 * jj;          // ascending -> lowest-idx kept
            const float* crow = cbq + (size_t)bin * D;
            double a = 0.0;
            for (int d = 0; d < D; d += 4) {
                const float4 rv = *(const float4*)&fbres[d];   // broadcast
                const float4 cv = *(const float4*)&crow[d];
                a = fma((double)rv.x, (double)cv.x, a);
                a = fma((double)rv.y, (double)cv.y, a);
                a = fma((double)rv.z, (double)cv.z, a);
                a = fma((double)rv.w, (double)cv.w, a);
            }
            const double s = fma(-2.0, a, cbn[q * BINS + bin]);
            if (s < bb) { bb = s; bbi = bin; }
        }
        redv[tid] = bb; redi[tid] = bbi;
        __syncthreads();
        for (int s2 = 128; s2 >= 1; s2 >>= 1) {
            if (tid < s2) {
                const double ov = redv[tid + s2]; const int oi = redi[tid + s2];
                if (ov < redv[tid] || (ov == redv[tid] && oi < redi[tid])) {
                    redv[tid] = ov; redi[tid] = oi;
                }
            }
            __syncthreads();
        }
        if (tid == 0) idxsL[tk2] = redi[0];
        __syncthreads();
    }

    // codes (final idx)
    if (tid < 64)
        out[OFF_C + (size_t)q * B * T + (size_t)b * T + t0 + tid] = (float)idxsL[tid];

    // ---- faithful f32 straight-through update (owners) + loss
    double lacc = 0.0;
    {
        const int myidx = idxsL[tok];
        const float* crow = cbq + (size_t)myidx * D + d0;
        #pragma unroll
        for (int i = 0; i < 64; i += 4) {
            const float4 qv = *(const float4*)(crow + i);
            float e, qst, dd;
            e = qv.x - rr[i];   qst = rr[i]   + e; dd = qst - rr[i];
            lacc = fma((double)dd, (double)dd, lacc); rr[i]   -= qst;
            e = qv.y - rr[i+1]; qst = rr[i+1] + e; dd = qst - rr[i+1];
            lacc = fma((double)dd, (double)dd, lacc); rr[i+1] -= qst;
            e = qv.z - rr[i+2]; qst = rr[i+2] + e; dd = qst - rr[i+2];
            lacc = fma((double)dd, (double)dd, lacc); rr[i+2] -= qst;
            e = qv.w - rr[i+3]; qst = rr[i+3] + e; dd = qst - rr[i+3];
            lacc = fma((double)dd, (double)dd, lacc); rr[i+3] -= qst;
        }
    }

    // ---- stage residual back out (coalesced), union reuse of resf
    __syncthreads();
    #pragma unroll
    for (int i = 0; i < 64; ++i) resf[tok * 257 + d0 + i] = rr[i];
    __syncthreads();
    for (int it = 0; it < 64; ++it) {
        const int lin = it * 256 + tid;
        const int tk = lin & 63, d = lin >> 6;
        rd[(size_t)d * T + tk] = resf[tk * 257 + d];
    }

    // ---- deterministic per-block loss partial
    redv[tid] = lacc;
    __syncthreads();
    for (int s2 = 128; s2 >= 1; s2 >>= 1) {
        if (tid < s2) redv[tid] += redv[tid + s2];
        __syncthreads();
    }
    if (tid == 0) lpart[(size_t)q * 1024 + bid] = redv[0];
}

// ---------------- final: quantized = x - res, in place on out[0:B*D*T) ----------
__global__ __launch_bounds__(256) void final_sub(const float* __restrict__ x,
                                                 float* __restrict__ o)
{
    const size_t i = ((size_t)blockIdx.x * 256 + threadIdx.x) * 4;
    const float4 xv = *(const float4*)(x + i);
    const float4 ov = *(const float4*)(o + i);
    float4 r;
    r.x = xv.x - ov.x; r.y = xv.y - ov.y; r.z = xv.z - ov.z; r.w = xv.w - ov.w;
    *(float4*)(o + i) = r;
}

// ---------------- OLD PATH (R2, known-good) kept as ws-size fallback ----------------
#define OTOK 32
#define ORS 260
__global__ __launch_bounds__(256, 3) void rvq_main_old(
    const float* __restrict__ x, const float* __restrict__ cb,
    const double* __restrict__ cbn, const float* __restrict__ cbnf,
    float* __restrict__ out, double* __restrict__ lpart)
{
    __shared__ float  res[OTOK][ORS];
    __shared__ float  bv1s[OTOK][16];
    __shared__ float  bv2s[OTOK][16];
    __shared__ int    bi1s[OTOK][16];
    __shared__ int    idxs[OTOK];
    __shared__ int    flags[OTOK];
    __shared__ double fbv[256];
    __shared__ int    fbi[256];

    const int tid = threadIdx.x;
    const int bid = blockIdx.x;
    const int b  = bid >> 7;
    const int t0 = (bid & 127) * OTOK;

    const float* xb = x + (size_t)b * D * T + t0;
    #pragma unroll
    for (int it = 0; it < 32; ++it) {
        const int d  = it * 8 + (tid >> 5);
        const int tk = tid & 31;
        res[tk][d] = xb[(size_t)d * T + tk];
    }
    __syncthreads();

    float qreg[32];
    #pragma unroll
    for (int i = 0; i < 32; ++i) qreg[i] = 0.0f;

    const int tg = tid & 15;
    const int bg = tid >> 4;
    const int tku = tid >> 3;
    const int d0u = (tid & 7) * 32;
    double lacc = 0.0;

    for (int q = 0; q < NQ; ++q) {
        const float*  cbq = cb   + (size_t)q * BINS * D;
        const float*  cnf = cbnf + (size_t)q * BINS;
        const double* cnd = cbn  + (size_t)q * BINS;

        float bvA = 3.4e38f, bvA2 = 3.4e38f;  int biA = 0;
        float bvB = 3.4e38f, bvB2 = 3.4e38f;  int biB = 0;

        for (int iter = 0; iter < 8; ++iter) {
            const int binbase = iter * 128 + bg * 8;
            float a0[8], a1[8];
            #pragma unroll
            for (int j = 0; j < 8; ++j) { a0[j] = 0.0f; a1[j] = 0.0f; }
            for (int d = 0; d < D; d += 4) {
                const float4 r0 = *(const float4*)&res[tg][d];
                const float4 r1 = *(const float4*)&res[tg + 16][d];
                #pragma unroll
                for (int j = 0; j < 8; ++j) {
                    const float4 c = *(const float4*)&cbq[(size_t)(binbase + j) * D + d];
                    a0[j] = fmaf(r0.x, c.x, a0[j]); a0[j] = fmaf(r0.y, c.y, a0[j]);
                    a0[j] = fmaf(r0.z, c.z, a0[j]); a0[j] = fmaf(r0.w, c.w, a0[j]);
                    a1[j] = fmaf(r1.x, c.x, a1[j]); a1[j] = fmaf(r1.y, c.y, a1[j]);
                    a1[j] = fmaf(r1.z, c.z, a1[j]); a1[j] = fmaf(r1.w, c.w, a1[j]);
                }
            }
            #pragma unroll
            for (int j = 0; j < 8; ++j) {
                const int bin = binbase + j;
                const float qn = cnf[bin];
                const float s0 = fmaf(-2.0f, a0[j], qn);
                const float s1 = fmaf(-2.0f, a1[j], qn);
                if (s0 < bvA) { bvA2 = bvA; bvA = s0; biA = bin; }
                else if (s0 < bvA2) { bvA2 = s0; }
                if (s1 < bvB) { bvB2 = bvB; bvB = s1; biB = bin; }
                else if (s1 < bvB2) { bvB2 = s1; }
            }
        }
        bv1s[tg][bg]      = bvA;  bv2s[tg][bg]      = bvA2;  bi1s[tg][bg]      = biA;
        bv1s[tg + 16][bg] = bvB;  bv2s[tg + 16][bg] = bvB2;  bi1s[tg + 16][bg] = biB;
        __syncthreads();

        if (tid < OTOK) {
            float g1 = bv1s[tid][0], g2 = bv2s[tid][0];
            int   gi = bi1s[tid][0];
            #pragma unroll
            for (int g = 1; g < 16; ++g) {
                const float v1 = bv1s[tid][g];
                const float v2 = bv2s[tid][g];
                const int   i1 = bi1s[tid][g];
                if (v1 < g1 || (v1 == g1 && i1 < gi)) { g2 = fminf(g1, v2); g1 = v1; gi = i1; }
                else g2 = fminf(g2, v1);
            }
            idxs[tid]  = gi;
            flags[tid] = (g2 - g1 < 0.02f) ? 1 : 0;
        }
        __syncthreads();

        for (int tok = 0; tok < OTOK; ++tok) {
            if (!flags[tok]) continue;
            double bb = 1e300; int bbi = 0;
            #pragma unroll
            for (int jj = 0; jj < 4; ++jj) {
                const int bin = tid + 256 * jj;
                const float* crow = cbq + (size_t)bin * D;
                double a = 0.0;
                for (int d = 0; d < D; d += 4) {
                    const float4 r = *(const float4*)&res[tok][d];
                    const float4 c = *(const float4*)&crow[d];
                    a = fma((double)r.x, (double)c.x, a);
                    a = fma((double)r.y, (double)c.y, a);
                    a = fma((double)r.z, (double)c.z, a);
                    a = fma((double)r.w, (double)c.w, a);
                }
                const double s = fma(-2.0, a, cnd[bin]);
                if (s < bb) { bb = s; bbi = bin; }
            }
            fbv[tid] = bb; fbi[tid] = bbi;
            __syncthreads();
            for (int s2 = 128; s2 >= 1; s2 >>= 1) {
                if (tid < s2) {
                    const double ov = fbv[tid + s2]; const int oi = fbi[tid + s2];
                    const double mv = fbv[tid];      const int mi = fbi[tid];
                    if (ov < mv || (ov == mv && oi < mi)) { fbv[tid] = ov; fbi[tid] = oi; }
                }
                __syncthreads();
            }
            if (tid == 0) idxs[tok] = fbi[0];
            __syncthreads();
        }

        if (tid < OTOK)
            out[OFF_C + (size_t)q * B * T + (size_t)b * T + t0 + tid] = (float)idxs[tid];

        const float* crow = cbq + (size_t)idxs[tku] * D;
        #pragma unroll
        for (int i = 0; i < 8; ++i) {
            const int d = d0u + i * 4;
            const float4 qv = *(const float4*)&crow[d];
            float4 r = *(float4*)&res[tku][d];
            float e, qst, dd;
            e = qv.x - r.x; qst = r.x + e; dd = qst - r.x;
            lacc = fma((double)dd, (double)dd, lacc); qreg[i*4+0] += qst; r.x = r.x - qst;
            e = qv.y - r.y; qst = r.y + e; dd = qst - r.y;
            lacc = fma((double)dd, (double)dd, lacc); qreg[i*4+1] += qst; r.y = r.y - qst;
            e = qv.z - r.z; qst = r.z + e; dd = qst - r.z;
            lacc = fma((double)dd, (double)dd, lacc); qreg[i*4+2] += qst; r.z = r.z - qst;
            e = qv.w - r.w; qst = r.w + e; dd = qst - r.w;
            lacc = fma((double)dd, (double)dd, lacc); qreg[i*4+3] += qst; r.w = r.w - qst;
            *(float4*)&res[tku][d] = r;
        }
        __syncthreads();
    }

    #pragma unroll
    for (int i = 0; i < 8; ++i)
        *(float4*)&res[tku][d0u + i * 4] = *(float4*)&qreg[i * 4];
    __syncthreads();
    #pragma unroll
    for (int it = 0; it < 32; ++it) {
        const int d  = it * 8 + (tid >> 5);
        const int tk = tid & 31;
        out[(size_t)b * D * T + (size_t)d * T + t0 + tk] = res[tk][d];
    }

    fbv[tid] = lacc;
    __syncthreads();
    for (int s2 = 128; s2 >= 1; s2 >>= 1) {
        if (tid < s2) fbv[tid] += fbv[tid + s2];
        __syncthreads();
    }
    if (tid == 0) lpart[bid] = fbv[0];
}

// ---------------- finalize: loss mean + bandwidth scalar ----------------
__global__ __launch_bounds__(256) void finalize_kernel(
    const double* __restrict__ lpart, int nblk,
    const int* __restrict__ srp, float* __restrict__ out)
{
    __shared__ double sh[256];
    double a = 0.0;
    for (int i = threadIdx.x; i < nblk; i += 256) a += lpart[i];
    sh[threadIdx.x] = a;
    __syncthreads();
    for (int s = 128; s >= 1; s >>= 1) {
        if (threadIdx.x < s) sh[threadIdx.x] += sh[threadIdx.x + s];
        __syncthreads();
    }
    if (threadIdx.x == 0) {
        out[OFF_L]  = (float)(sh[0] / ((double)NQ * B * T * D));
        out[OFF_BW] = (float)((double)NQ * 10.0 * (double)srp[0] / 1000.0);
    }
}

extern "C" void kernel_launch(void* const* d_in, const int* in_sizes, int n_in,
                              void* d_out, int out_size, void* d_ws, size_t ws_size,
                              hipStream_t stream)
{
    const float* x  = (const float*)d_in[0];
    const float* cb = (const float*)d_in[1];
    const int*   sr = (const int*)d_in[2];
    float* out = (float*)d_out;

    // ws layout: cbn f64[8192] @0 (65536) | cbnf f32[8192] @65536 (32768)
    //            lpart f64[8192] @98304 (65536) | bfh @163840 (4 MiB) | bfl @4358144
    //            total 8552448 B
    double* cbn   = (double*)d_ws;
    float*  cbnf  = (float*)((char*)d_ws + 65536);
    double* lpart = (double*)((char*)d_ws + 98304);
    unsigned short* bfh = (unsigned short*)((char*)d_ws + 163840);
    unsigned short* bfl = (unsigned short*)((char*)d_ws + 4358144);

    hipLaunchKernelGGL(cbnorm_kernel, dim3(NQ * BINS / 4), dim3(256), 0, stream, cb, cbn, cbnf);

    if (ws_size >= (size_t)8552448) {
        hipLaunchKernelGGL(prep_bfrag, dim3(1024), dim3(256), 0, stream, cb, bfh, bfl);
        float* resb = out;   // quantized section doubles as residual buffer
        for (int q = 0; q < NQ; ++q) {
            hipLaunchKernelGGL(rvq_scan, dim3(B * (T / 64)), dim3(256), 0, stream,
                               (q == 0 ? x : (const float*)resb), resb, cb, cbn, cbnf,
                               bfh, bfl, out, lpart, q);
        }
        hipLaunchKernelGGL(final_sub, dim3((B * D * T) / 1024), dim3(256), 0, stream, x, resb);
        hipLaunchKernelGGL(finalize_kernel, dim3(1), dim3(256), 0, stream,
                           lpart, NQ * 1024, sr, out);
    } else {
        hipLaunchKernelGGL(rvq_main_old, dim3(B * (T / OTOK)), dim3(256), 0, stream,
                           x, cb, cbn, cbnf, out, lpart);
        hipLaunchKernelGGL(finalize_kernel, dim3(1), dim3(256), 0, stream,
                           lpart, B * (T / OTOK), sr, out);
    }
}

// Round 5
// 4674.409 us; speedup vs baseline: 1.3674x; 1.3674x over previous
//
#include <hip/hip_runtime.h>

#define B 16
#define D 256
#define T 4096
#define NQ 8
#define BINS 1024
#define EPS 0.008f

#define OFF_C  ((size_t)B * D * T)            // quantized elems = 16777216
#define OFF_BW (OFF_C + (size_t)NQ * B * T)   // + codes 524288 -> 17301504
#define OFF_L  (OFF_BW + 1)

// A-plane LDS row stride in bytes (544 = 34*16) + XOR swizzle on bits 4-5
#define ARS 544

typedef __attribute__((ext_vector_type(8))) short short8v;
typedef __attribute__((ext_vector_type(4))) float float4v;

__device__ __forceinline__ unsigned short f2bf(float f) {
    unsigned u = __float_as_uint(f);
    unsigned r = (u + 0x7fffu + ((u >> 16) & 1u)) >> 16;   // RNE
    return (unsigned short)r;
}
__device__ __forceinline__ float bf2f(unsigned short h) {
    return __uint_as_float(((unsigned)h) << 16);
}

// ---------------- codebook norms: f64 (exact fallback) + f32 (scan) ----------------
__global__ __launch_bounds__(256) void cbnorm_kernel(const float* __restrict__ cb,
                                                     double* __restrict__ cbn,
                                                     float* __restrict__ cbnf)
{
    const int wave = threadIdx.x >> 6;
    const int lane = threadIdx.x & 63;
    const int bin = blockIdx.x * 4 + wave;          // 0..8191 (q*1024+k)
    const float4 v = *(const float4*)&cb[(size_t)bin * D + lane * 4];
    double a = (double)v.x * v.x + (double)v.y * v.y
             + (double)v.z * v.z + (double)v.w * v.w;
    #pragma unroll
    for (int off = 32; off >= 1; off >>= 1)
        a += __shfl_xor(a, off, 64);
    if (lane == 0) { cbn[bin] = a; cbnf[bin] = (float)a; }
}

// ---------------- prep: codebook -> bf16 hi/lo planes in MFMA-B-fragment order ----
// frag c = q*512 + ntg*8 + ks ; lane l, j -> B[k=ks*32+(l>>4)*8+j][n=ntg*16+(l&15)]
__global__ __launch_bounds__(256) void prep_bfrag(const float* __restrict__ cb,
                                                  unsigned short* __restrict__ bfh,
                                                  unsigned short* __restrict__ bfl)
{
    const int c = blockIdx.x * 4 + (threadIdx.x >> 6);   // 0..4095
    const int lane = threadIdx.x & 63;
    const int q = c >> 9, ntg = (c >> 3) & 63, ks = c & 7;
    const float* src = cb + ((size_t)q * BINS + ntg * 16 + (lane & 15)) * D
                         + ks * 32 + (lane >> 4) * 8;
    short8v h, l;
    #pragma unroll
    for (int j = 0; j < 8; ++j) {
        const float v = src[j];
        const unsigned short hh = f2bf(v);
        h[j] = (short)hh;
        l[j] = (short)f2bf(v - bf2f(hh));
    }
    const size_t off = ((size_t)c * 64 + lane) * 8;
    *(short8v*)(bfh + off) = h;
    *(short8v*)(bfl + off) = l;
}

// ---------------- per-stage scan+update kernel (one launch per q) ----------------
// 64 tokens/block, 4 waves; wave w scans bins [w*256, w*256+256).
// LDS (bytes):
//  0     : union { A_hi[64][ARS] @0, A_lo @34816 -> 69632 | resf f32[64*257]=65792 }
//  69632 : norms f32[1024]   -> 73728
//  73728 : mg1 f32[256]      -> 74752
//  74752 : mg2 f32[256]      -> 75776
//  75776 : mgi i32[256]      -> 76800
//  76800 : idxsL i32[64]     -> 77056
//  77056 : flagsL i32[64]    -> 77312
//  77312 : rstage f32[256]   -> 78336
//  78336 : redv f64[256]     -> 80384
//  80384 : redi i32[256]     -> 81408   (2 blocks/CU: 162816 <= 163840)
__global__ __launch_bounds__(256, 2) void rvq_scan(
    const float* __restrict__ rsrc, float* __restrict__ rdst,
    const float* __restrict__ cb,
    const double* __restrict__ cbn, const float* __restrict__ cbnf,
    const unsigned short* __restrict__ bfh, const unsigned short* __restrict__ bfl,
    float* __restrict__ out, double* __restrict__ lpart, int q)
{
    __shared__ __align__(16) char smem[81408];
    char*   smc   = smem;
    float*  resf  = (float*)smem;
    float*  norms = (float*)(smem + 69632);
    float*  mg1   = (float*)(smem + 73728);
    float*  mg2   = (float*)(smem + 74752);
    int*    mgi   = (int*)(smem + 75776);
    int*    idxsL = (int*)(smem + 76800);
    int*    flagsL= (int*)(smem + 77056);
    float*  rstage= (float*)(smem + 77312);
    double* redv  = (double*)(smem + 78336);
    int*    redi  = (int*)(smem + 80384);

    const int tid  = threadIdx.x;
    const int bid  = blockIdx.x;
    const int b    = bid >> 6;
    const int t0   = (bid & 63) * 64;
    const int w    = tid >> 6;
    const int lane = tid & 63;
    const int tok  = tid >> 2;          // owner token (0..63)
    const int d0   = (tid & 3) * 64;    // owner dim base

    const float* rs = rsrc + (size_t)b * D * T + t0;
    float*       rd = rdst + (size_t)b * D * T + t0;

    // ---- 1. stage residual tile global->LDS (coalesced along t, transpose)
    for (int it = 0; it < 64; ++it) {
        const int lin = it * 256 + tid;
        resf[(lin & 63) * 257 + (lin >> 6)] = rs[(size_t)(lin >> 6) * T + (lin & 63)];
    }
    __syncthreads();

    // ---- 2. encode own token row to bf16 hi/lo regs (transient)
    short8v hs[8], ls[8];
    #pragma unroll
    for (int c = 0; c < 8; ++c) {
        #pragma unroll
        for (int j = 0; j < 8; ++j) {
            const float v = resf[tok * 257 + d0 + c * 8 + j];
            const unsigned short hh = f2bf(v);
            hs[c][j] = (short)hh;
            ls[c][j] = (short)f2bf(v - bf2f(hh));
        }
    }
    __syncthreads();   // resf reads done; union becomes A planes

    // ---- 3. write A planes (XOR-swizzled) + norms
    {
        const int xkt = ((tok >> 2) & 3) << 4;
        #pragma unroll
        for (int c = 0; c < 8; ++c) {
            const int byo = tok * ARS + ((d0 * 2 + c * 16) ^ xkt);
            *(short8v*)(smc + byo) = hs[c];
            *(short8v*)(smc + 34816 + byo) = ls[c];
        }
    }
    for (int i = tid; i < BINS; i += 256) norms[i] = cbnf[q * BINS + i];
    __syncthreads();

    // ---- 4. distance scan via split-bf16 MFMA (3 products: Al*Bh, Ah*Bl, Ah*Bh)
    float bv1[16], bv2[16]; int bi1[16];
    #pragma unroll
    for (int s = 0; s < 16; ++s) { bv1[s] = 3.4e38f; bv2[s] = 3.4e38f; bi1[s] = 0; }

    const unsigned short* phw = bfh + ((size_t)q * 512 + w * 128) * 512 + lane * 8;
    const unsigned short* plw = bfl + ((size_t)q * 512 + w * 128) * 512 + lane * 8;
    const int col = lane & 15;
    const int dbx = ((lane >> 4) * 16) ^ (((col >> 2) & 3) << 4);
    const int arow0 = (col) * ARS;
    const int arow1 = (16 + col) * ARS;
    const int arow2 = (32 + col) * ARS;
    const int arow3 = (48 + col) * ARS;

    #pragma unroll 1
    for (int nt = 0; nt < 16; ++nt) {
        float4v acc0 = {0,0,0,0}, acc1 = {0,0,0,0}, acc2 = {0,0,0,0}, acc3 = {0,0,0,0};
        #pragma unroll
        for (int ks = 0; ks < 8; ++ks) {
            const short8v Bh = *(const short8v*)(phw + (size_t)(nt * 8 + ks) * 512);
            const short8v Bl = *(const short8v*)(plw + (size_t)(nt * 8 + ks) * 512);
            const int dby = ks * 64 + dbx;
            #define MTSTEP(AR, ACC) { \
                const short8v Ah = *(const short8v*)(smc + (AR) + dby); \
                const short8v Al = *(const short8v*)(smc + 34816 + (AR) + dby); \
                ACC = __builtin_amdgcn_mfma_f32_16x16x32_bf16(Al, Bh, ACC, 0, 0, 0); \
                ACC = __builtin_amdgcn_mfma_f32_16x16x32_bf16(Ah, Bl, ACC, 0, 0, 0); \
                ACC = __builtin_amdgcn_mfma_f32_16x16x32_bf16(Ah, Bh, ACC, 0, 0, 0); }
            MTSTEP(arow0, acc0) MTSTEP(arow1, acc1) MTSTEP(arow2, acc2) MTSTEP(arow3, acc3)
            #undef MTSTEP
        }
        const int ntg = w * 16 + nt;
        const float qn  = norms[ntg * 16 + col];
        const int   bin = ntg * 16 + col;
        #define EPI(MT, ACC) { \
            _Pragma("unroll") \
            for (int r = 0; r < 4; ++r) { \
                const float s = fmaf(-2.0f, ACC[r], qn); \
                const int sl = MT * 4 + r; \
                if (s < bv1[sl]) { bv2[sl] = bv1[sl]; bv1[sl] = s; bi1[sl] = bin; } \
                else if (s < bv2[sl]) bv2[sl] = s; } }
        EPI(0, acc0) EPI(1, acc1) EPI(2, acc2) EPI(3, acc3)
        #undef EPI
    }

    // ---- 5. top-2 merge across the 16 cols, index tiebreak
    #pragma unroll
    for (int off = 1; off <= 8; off <<= 1) {
        #pragma unroll
        for (int sl = 0; sl < 16; ++sl) {
            const float ov1 = __shfl_xor(bv1[sl], off, 64);
            const float ov2 = __shfl_xor(bv2[sl], off, 64);
            const int   oi  = __shfl_xor(bi1[sl], off, 64);
            if (ov1 < bv1[sl] || (ov1 == bv1[sl] && oi < bi1[sl])) {
                bv2[sl] = fminf(bv1[sl], ov2); bv1[sl] = ov1; bi1[sl] = oi;
            } else {
                bv2[sl] = fminf(bv2[sl], ov1);
            }
        }
    }
    if ((lane & 15) == 0) {
        const int rg = lane >> 4;
        #pragma unroll
        for (int mt = 0; mt < 4; ++mt)
            #pragma unroll
            for (int r = 0; r < 4; ++r) {
                const int tk = mt * 16 + rg * 4 + r;
                const int sl = mt * 4 + r;
                mg1[tk * 4 + w] = bv1[sl];
                mg2[tk * 4 + w] = bv2[sl];
                mgi[tk * 4 + w] = bi1[sl];
            }
    }
    __syncthreads();

    if (tid < 64) {
        float g1 = mg1[tid*4], g2 = mg2[tid*4]; int gi = mgi[tid*4];
        #pragma unroll
        for (int wv = 1; wv < 4; ++wv) {
            const float v1 = mg1[tid*4+wv], v2 = mg2[tid*4+wv];
            const int   i1 = mgi[tid*4+wv];
            if (v1 < g1 || (v1 == g1 && i1 < gi)) { g2 = fminf(g1, v2); g1 = v1; gi = i1; }
            else g2 = fminf(g2, v1);
        }
        idxsL[tid]  = gi;
        flagsL[tid] = (g2 - g1 < EPS) ? 1 : 0;
    }
    __syncthreads();

    // ---- 6. exact f64 full-scan fallback for near-tie tokens (rare: ~0-2/block)
    const float* cbq = cb + (size_t)q * BINS * D;
    #pragma unroll 1
    for (int tk2 = 0; tk2 < 64; ++tk2) {
        if (!flagsL[tk2]) continue;                  // uniform branch (LDS)
        rstage[tid] = rs[(size_t)tid * T + tk2];     // stage full r row (tid == d)
        __syncthreads();
        double bb = 1e300; int bbi = 0;
        #pragma unroll 1
        for (int jj = 0; jj < 4; ++jj) {
            const int bin = tid + 256 * jj;          // ascending -> lowest-idx kept
            const float* crow = cbq + (size_t)bin * D;
            double a = 0.0;
            for (int d = 0; d < D; d += 4) {
                const float4 rv = *(const float4*)&rstage[d];
                const float4 cv = *(const float4*)&crow[d];
                a = fma((double)rv.x, (double)cv.x, a);
                a = fma((double)rv.y, (double)cv.y, a);
                a = fma((double)rv.z, (double)cv.z, a);
                a = fma((double)rv.w, (double)cv.w, a);
            }
            const double s = fma(-2.0, a, cbn[q * BINS + bin]);
            if (s < bb) { bb = s; bbi = bin; }
        }
        redv[tid] = bb; redi[tid] = bbi;
        __syncthreads();
        for (int s2 = 128; s2 >= 1; s2 >>= 1) {
            if (tid < s2) {
                const double ov = redv[tid + s2]; const int oi = redi[tid + s2];
                if (ov < redv[tid] || (ov == redv[tid] && oi < redi[tid])) {
                    redv[tid] = ov; redi[tid] = oi;
                }
            }
            __syncthreads();
        }
        if (tid == 0) idxsL[tk2] = redi[0];
        __syncthreads();
    }

    // ---- 7. codes
    if (tid < 64)
        out[OFF_C + (size_t)q * B * T + (size_t)b * T + t0 + tid] = (float)idxsL[tid];

    // ---- 8. faithful f32 straight-through update in coalesced mapping + loss
    //         (re-read residual from global; gather codebook row — L2-hot)
    double lacc = 0.0;
    for (int it = 0; it < 64; ++it) {
        const int lin = it * 256 + tid;
        const int tk = lin & 63;
        const int d  = lin >> 6;
        const float r  = rs[(size_t)d * T + tk];
        const float cv = cbq[(size_t)idxsL[tk] * D + d];
        const float e   = cv - r;
        const float qst = r + e;
        const float dd  = qst - r;
        lacc = fma((double)dd, (double)dd, lacc);
        rd[(size_t)d * T + tk] = r - qst;
    }

    // ---- 9. deterministic per-block loss partial
    redv[tid] = lacc;
    __syncthreads();
    for (int s2 = 128; s2 >= 1; s2 >>= 1) {
        if (tid < s2) redv[tid] += redv[tid + s2];
        __syncthreads();
    }
    if (tid == 0) lpart[(size_t)q * 1024 + bid] = redv[0];
}

// ---------------- final: quantized = x - res, in place on out[0:B*D*T) ----------
__global__ __launch_bounds__(256) void final_sub(const float* __restrict__ x,
                                                 float* __restrict__ o)
{
    const size_t i = ((size_t)blockIdx.x * 256 + threadIdx.x) * 4;
    const float4 xv = *(const float4*)(x + i);
    const float4 ov = *(const float4*)(o + i);
    float4 r;
    r.x = xv.x - ov.x; r.y = xv.y - ov.y; r.z = xv.z - ov.z; r.w = xv.w - ov.w;
    *(float4*)(o + i) = r;
}

// ---------------- OLD PATH (R2, known-good) kept as ws-size fallback ----------------
#define OTOK 32
#define ORS 260
__global__ __launch_bounds__(256, 3) void rvq_main_old(
    const float* __restrict__ x, const float* __restrict__ cb,
    const double* __restrict__ cbn, const float* __restrict__ cbnf,
    float* __restrict__ out, double* __restrict__ lpart)
{
    __shared__ float  res[OTOK][ORS];
    __shared__ float  bv1s[OTOK][16];
    __shared__ float  bv2s[OTOK][16];
    __shared__ int    bi1s[OTOK][16];
    __shared__ int    idxs[OTOK];
    __shared__ int    flags[OTOK];
    __shared__ double fbv[256];
    __shared__ int    fbi[256];

    const int tid = threadIdx.x;
    const int bid = blockIdx.x;
    const int b  = bid >> 7;
    const int t0 = (bid & 127) * OTOK;

    const float* xb = x + (size_t)b * D * T + t0;
    #pragma unroll
    for (int it = 0; it < 32; ++it) {
        const int d  = it * 8 + (tid >> 5);
        const int tk = tid & 31;
        res[tk][d] = xb[(size_t)d * T + tk];
    }
    __syncthreads();

    float qreg[32];
    #pragma unroll
    for (int i = 0; i < 32; ++i) qreg[i] = 0.0f;

    const int tg = tid & 15;
    const int bg = tid >> 4;
    const int tku = tid >> 3;
    const int d0u = (tid & 7) * 32;
    double lacc = 0.0;

    for (int q = 0; q < NQ; ++q) {
        const float*  cbq = cb   + (size_t)q * BINS * D;
        const float*  cnf = cbnf + (size_t)q * BINS;
        const double* cnd = cbn  + (size_t)q * BINS;

        float bvA = 3.4e38f, bvA2 = 3.4e38f;  int biA = 0;
        float bvB = 3.4e38f, bvB2 = 3.4e38f;  int biB = 0;

        for (int iter = 0; iter < 8; ++iter) {
            const int binbase = iter * 128 + bg * 8;
            float a0[8], a1[8];
            #pragma unroll
            for (int j = 0; j < 8; ++j) { a0[j] = 0.0f; a1[j] = 0.0f; }
            for (int d = 0; d < D; d += 4) {
                const float4 r0 = *(const float4*)&res[tg][d];
                const float4 r1 = *(const float4*)&res[tg + 16][d];
                #pragma unroll
                for (int j = 0; j < 8; ++j) {
                    const float4 c = *(const float4*)&cbq[(size_t)(binbase + j) * D + d];
                    a0[j] = fmaf(r0.x, c.x, a0[j]); a0[j] = fmaf(r0.y, c.y, a0[j]);
                    a0[j] = fmaf(r0.z, c.z, a0[j]); a0[j] = fmaf(r0.w, c.w, a0[j]);
                    a1[j] = fmaf(r1.x, c.x, a1[j]); a1[j] = fmaf(r1.y, c.y, a1[j]);
                    a1[j] = fmaf(r1.z, c.z, a1[j]); a1[j] = fmaf(r1.w, c.w, a1[j]);
                }
            }
            #pragma unroll
            for (int j = 0; j < 8; ++j) {
                const int bin = binbase + j;
                const float qn = cnf[bin];
                const float s0 = fmaf(-2.0f, a0[j], qn);
                const float s1 = fmaf(-2.0f, a1[j], qn);
                if (s0 < bvA) { bvA2 = bvA; bvA = s0; biA = bin; }
                else if (s0 < bvA2) { bvA2 = s0; }
                if (s1 < bvB) { bvB2 = bvB; bvB = s1; biB = bin; }
                else if (s1 < bvB2) { bvB2 = s1; }
            }
        }
        bv1s[tg][bg]      = bvA;  bv2s[tg][bg]      = bvA2;  bi1s[tg][bg]      = biA;
        bv1s[tg + 16][bg] = bvB;  bv2s[tg + 16][bg] = bvB2;  bi1s[tg + 16][bg] = biB;
        __syncthreads();

        if (tid < OTOK) {
            float g1 = bv1s[tid][0], g2 = bv2s[tid][0];
            int   gi = bi1s[tid][0];
            #pragma unroll
            for (int g = 1; g < 16; ++g) {
                const float v1 = bv1s[tid][g];
                const float v2 = bv2s[tid][g];
                const int   i1 = bi1s[tid][g];
                if (v1 < g1 || (v1 == g1 && i1 < gi)) { g2 = fminf(g1, v2); g1 = v1; gi = i1; }
                else g2 = fminf(g2, v1);
            }
            idxs[tid]  = gi;
            flags[tid] = (g2 - g1 < 0.02f) ? 1 : 0;
        }
        __syncthreads();

        for (int tok = 0; tok < OTOK; ++tok) {
            if (!flags[tok]) continue;
            double bb = 1e300; int bbi = 0;
            #pragma unroll
            for (int jj = 0; jj < 4; ++jj) {
                const int bin = tid + 256 * jj;
                const float* crow = cbq + (size_t)bin * D;
                double a = 0.0;
                for (int d = 0; d < D; d += 4) {
                    const float4 r = *(const float4*)&res[tok][d];
                    const float4 c = *(const float4*)&crow[d];
                    a = fma((double)r.x, (double)c.x, a);
                    a = fma((double)r.y, (double)c.y, a);
                    a = fma((double)r.z, (double)c.z, a);
                    a = fma((double)r.w, (double)c.w, a);
                }
                const double s = fma(-2.0, a, cnd[bin]);
                if (s < bb) { bb = s; bbi = bin; }
            }
            fbv[tid] = bb; fbi[tid] = bbi;
            __syncthreads();
            for (int s2 = 128; s2 >= 1; s2 >>= 1) {
                if (tid < s2) {
                    const double ov = fbv[tid + s2]; const int oi = fbi[tid + s2];
                    const double mv = fbv[tid];      const int mi = fbi[tid];
                    if (ov < mv || (ov == mv && oi < mi)) { fbv[tid] = ov; fbi[tid] = oi; }
                }
                __syncthreads();
            }
            if (tid == 0) idxs[tok] = fbi[0];
            __syncthreads();
        }

        if (tid < OTOK)
            out[OFF_C + (size_t)q * B * T + (size_t)b * T + t0 + tid] = (float)idxs[tid];

        const float* crow = cbq + (size_t)idxs[tku] * D;
        #pragma unroll
        for (int i = 0; i < 8; ++i) {
            const int d = d0u + i * 4;
            const float4 qv = *(const float4*)&crow[d];
            float4 r = *(float4*)&res[tku][d];
            float e, qst, dd;
            e = qv.x - r.x; qst = r.x + e; dd = qst - r.x;
            lacc = fma((double)dd, (double)dd, lacc); qreg[i*4+0] += qst; r.x = r.x - qst;
            e = qv.y - r.y; qst = r.y + e; dd = qst - r.y;
            lacc = fma((double)dd, (double)dd, lacc); qreg[i*4+1] += qst; r.y = r.y - qst;
            e = qv.z - r.z; qst = r.z + e; dd = qst - r.z;
            lacc = fma((double)dd, (double)dd, lacc); qreg[i*4+2] += qst; r.z = r.z - qst;
            e = qv.w - r.w; qst = r.w + e; dd = qst - r.w;
            lacc = fma((double)dd, (double)dd, lacc); qreg[i*4+3] += qst; r.w = r.w - qst;
            *(float4*)&res[tku][d] = r;
        }
        __syncthreads();
    }

    #pragma unroll
    for (int i = 0; i < 8; ++i)
        *(float4*)&res[tku][d0u + i * 4] = *(float4*)&qreg[i * 4];
    __syncthreads();
    #pragma unroll
    for (int it = 0; it < 32; ++it) {
        const int d  = it * 8 + (tid >> 5);
        const int tk = tid & 31;
        out[(size_t)b * D * T + (size_t)d * T + t0 + tk] = res[tk][d];
    }

    fbv[tid] = lacc;
    __syncthreads();
    for (int s2 = 128; s2 >= 1; s2 >>= 1) {
        if (tid < s2) fbv[tid] += fbv[tid + s2];
        __syncthreads();
    }
    if (tid == 0) lpart[bid] = fbv[0];
}

// ---------------- finalize: loss mean + bandwidth scalar ----------------
__global__ __launch_bounds__(256) void finalize_kernel(
    const double* __restrict__ lpart, int nblk,
    const int* __restrict__ srp, float* __restrict__ out)
{
    __shared__ double sh[256];
    double a = 0.0;
    for (int i = threadIdx.x; i < nblk; i += 256) a += lpart[i];
    sh[threadIdx.x] = a;
    __syncthreads();
    for (int s = 128; s >= 1; s >>= 1) {
        if (threadIdx.x < s) sh[threadIdx.x] += sh[threadIdx.x + s];
        __syncthreads();
    }
    if (threadIdx.x == 0) {
        out[OFF_L]  = (float)(sh[0] / ((double)NQ * B * T * D));
        out[OFF_BW] = (float)((double)NQ * 10.0 * (double)srp[0] / 1000.0);
    }
}

extern "C" void kernel_launch(void* const* d_in, const int* in_sizes, int n_in,
                              void* d_out, int out_size, void* d_ws, size_t ws_size,
                              hipStream_t stream)
{
    const float* x  = (const float*)d_in[0];
    const float* cb = (const float*)d_in[1];
    const int*   sr = (const int*)d_in[2];
    float* out = (float*)d_out;

    // ws layout: cbn f64[8192] @0 (65536) | cbnf f32[8192] @65536 (32768)
    //            lpart f64[8192] @98304 (65536) | bfh @163840 (4 MiB) | bfl @4358144
    //            total 8552448 B
    double* cbn   = (double*)d_ws;
    float*  cbnf  = (float*)((char*)d_ws + 65536);
    double* lpart = (double*)((char*)d_ws + 98304);
    unsigned short* bfh = (unsigned short*)((char*)d_ws + 163840);
    unsigned short* bfl = (unsigned short*)((char*)d_ws + 4358144);

    hipLaunchKernelGGL(cbnorm_kernel, dim3(NQ * BINS / 4), dim3(256), 0, stream, cb, cbn, cbnf);

    if (ws_size >= (size_t)8552448) {
        hipLaunchKernelGGL(prep_bfrag, dim3(1024), dim3(256), 0, stream, cb, bfh, bfl);
        float* resb = out;   // quantized section doubles as residual buffer
        for (int q = 0; q < NQ; ++q) {
            hipLaunchKernelGGL(rvq_scan, dim3(B * (T / 64)), dim3(256), 0, stream,
                               (q == 0 ? x : (const float*)resb), resb, cb, cbn, cbnf,
                               bfh, bfl, out, lpart, q);
        }
        hipLaunchKernelGGL(final_sub, dim3((B * D * T) / 1024), dim3(256), 0, stream, x, resb);
        hipLaunchKernelGGL(finalize_kernel, dim3(1), dim3(256), 0, stream,
                           lpart, NQ * 1024, sr, out);
    } else {
        hipLaunchKernelGGL(rvq_main_old, dim3(B * (T / OTOK)), dim3(256), 0, stream,
                           x, cb, cbn, cbnf, out, lpart);
        hipLaunchKernelGGL(finalize_kernel, dim3(1), dim3(256), 0, stream,
                           lpart, B * (T / OTOK), sr, out);
    }
}

// Round 7
// 2713.616 us; speedup vs baseline: 2.3555x; 1.7226x over previous
//
#include <hip/hip_runtime.h>

#define B 16
#define D 256
#define T 4096
#define NQ 8
#define BINS 1024
#define EPS 0.008f

#define OFF_C  ((size_t)B * D * T)            // quantized elems = 16777216
#define OFF_BW (OFF_C + (size_t)NQ * B * T)   // + codes 524288 -> 17301504
#define OFF_L  (OFF_BW + 1)

typedef __attribute__((ext_vector_type(8))) short short8v;
typedef __attribute__((ext_vector_type(4))) float float4v;

// ---- LDS map (bytes) for rvq_scan (512 threads, 1 block/CU) ----
#define BBUF   0        // 2 x 32768 B double buffer   (union with RESF)
#define RESF   0        // f32[64*257] = 65792 (transient: staging + A-build only)
#define NORMS  65792    // f32[1024]  -> 69888
#define MG1    69888    // f32[256]   -> 70912
#define MG2    70912    // f32[256]   -> 71936
#define MGI    71936    // i32[256]   -> 72960
#define IDXS   72960    // i32[128]   -> 73472
#define FLAGS  73472    // i32[128]   -> 73984
#define RSTG   73984    // f32[256]   -> 75008
#define REDV   75008    // f64[512]   -> 79104
#define REDI   79104    // i32[512]   -> 81152
#define SMTOT  81152

#define STAGE16(gp, loff) \
  __builtin_amdgcn_global_load_lds( \
      (const __attribute__((address_space(1))) unsigned int*)(gp), \
      (__attribute__((address_space(3))) unsigned int*)(smc + (loff)), 16, 0, 0)

__device__ __forceinline__ unsigned short f2bf(float f) {
    unsigned u = __float_as_uint(f);
    unsigned r = (u + 0x7fffu + ((u >> 16) & 1u)) >> 16;   // RNE
    return (unsigned short)r;
}
__device__ __forceinline__ float bf2f(unsigned short h) {
    return __uint_as_float(((unsigned)h) << 16);
}

// ---------------- codebook norms: f64 (exact fallback) + f32 (scan) ----------------
__global__ __launch_bounds__(256) void cbnorm_kernel(const float* __restrict__ cb,
                                                     double* __restrict__ cbn,
                                                     float* __restrict__ cbnf)
{
    const int wave = threadIdx.x >> 6;
    const int lane = threadIdx.x & 63;
    const int bin = blockIdx.x * 4 + wave;          // 0..8191 (q*1024+k)
    const float4 v = *(const float4*)&cb[(size_t)bin * D + lane * 4];
    double a = (double)v.x * v.x + (double)v.y * v.y
             + (double)v.z * v.z + (double)v.w * v.w;
    #pragma unroll
    for (int off = 32; off >= 1; off >>= 1)
        a += __shfl_xor(a, off, 64);
    if (lane == 0) { cbn[bin] = a; cbnf[bin] = (float)a; }
}

// ---------------- prep: codebook -> bf16 hi/lo planes in MFMA-B-fragment order ----
// frag c = q*512 + ntg*8 + ks ; lane l, j -> B[k=ks*32+(l>>4)*8+j][n=ntg*16+(l&15)]
__global__ __launch_bounds__(256) void prep_bfrag(const float* __restrict__ cb,
                                                  unsigned short* __restrict__ bfh,
                                                  unsigned short* __restrict__ bfl)
{
    const int c = blockIdx.x * 4 + (threadIdx.x >> 6);   // 0..4095
    const int lane = threadIdx.x & 63;
    const int q = c >> 9, ntg = (c >> 3) & 63, ks = c & 7;
    const float* src = cb + ((size_t)q * BINS + ntg * 16 + (lane & 15)) * D
                         + ks * 32 + (lane >> 4) * 8;
    short8v h, l;
    #pragma unroll
    for (int j = 0; j < 8; ++j) {
        const float v = src[j];
        const unsigned short hh = f2bf(v);
        h[j] = (short)hh;
        l[j] = (short)f2bf(v - bf2f(hh));
    }
    const size_t off = ((size_t)c * 64 + lane) * 8;
    *(short8v*)(bfh + off) = h;
    *(short8v*)(bfl + off) = l;
}

// ---------------- per-stage scan+update (one launch per q) ----------------
// 512 threads, 128 tokens/block, 8 waves: tw = w>>1 (token group, 32 tok),
// bw = w&1 (bin half, 512 bins). A hi/lo in registers; B via LDS double buffer.
__global__ __launch_bounds__(512, 2) void rvq_scan(
    const float* __restrict__ rsrc, float* __restrict__ rdst,
    const float* __restrict__ cb,
    const double* __restrict__ cbn, const float* __restrict__ cbnf,
    const unsigned short* __restrict__ bfh, const unsigned short* __restrict__ bfl,
    float* __restrict__ out, double* __restrict__ lpart, int q)
{
    __shared__ __align__(16) char smem[SMTOT];
    char*   smc    = smem;
    float*  resf   = (float*)(smem + RESF);
    float*  normsp = (float*)(smem + NORMS);
    float*  mg1    = (float*)(smem + MG1);
    float*  mg2    = (float*)(smem + MG2);
    int*    mgi    = (int*)(smem + MGI);
    int*    idxsL  = (int*)(smem + IDXS);
    int*    flagsL = (int*)(smem + FLAGS);
    float*  rstage = (float*)(smem + RSTG);
    double* redv   = (double*)(smem + REDV);
    int*    redi   = (int*)(smem + REDI);

    const int tid  = threadIdx.x;
    const int bid  = blockIdx.x;
    const int b    = bid >> 5;            // T/128 = 32 tiles per batch
    const int t0   = (bid & 31) * 128;
    const int w    = tid >> 6;            // 0..7
    const int lane = tid & 63;
    const int col  = lane & 15;
    const int rgrp = lane >> 4;
    const int bw   = w & 1;               // bin half
    const int rot  = (bid * 5) & 31;      // per-block bin-group rotation (L2 spread)

    const float* rs = rsrc + (size_t)b * D * T + t0;
    float*       rd = rdst + (size_t)b * D * T + t0;

    // ---- A-fragments in registers: 32 tokens/wave, K=256, hi+lo planes
    short8v Ah0[8], Al0[8], Ah1[8], Al1[8];
    {
        const int mychunk = w >> 2;                 // tokens [chunk*64, chunk*64+64)
        const int rowb    = ((w >> 1) & 1) * 32;    // row base within chunk
        #pragma unroll 1
        for (int ch = 0; ch < 2; ++ch) {
            // stage chunk ch of the residual tile into resf (coalesced, nontemporal)
            #pragma unroll 1
            for (int it = 0; it < 32; ++it) {
                const int lin = it * 512 + tid;
                const int tkl = lin & 63, d = lin >> 6;
                resf[tkl * 257 + d] =
                    __builtin_nontemporal_load(&rs[(size_t)d * T + ch * 64 + tkl]);
            }
            __syncthreads();
            if (mychunk == ch) {
                #pragma unroll
                for (int mt = 0; mt < 2; ++mt) {
                    #pragma unroll
                    for (int ks = 0; ks < 8; ++ks) {
                        short8v h, l;
                        #pragma unroll
                        for (int j = 0; j < 8; ++j) {
                            const float v =
                                resf[(rowb + mt * 16 + col) * 257 + ks * 32 + rgrp * 8 + j];
                            const unsigned short hh = f2bf(v);
                            h[j] = (short)hh;
                            l[j] = (short)f2bf(v - bf2f(hh));
                        }
                        if (mt == 0) { Ah0[ks] = h; Al0[ks] = l; }
                        else         { Ah1[ks] = h; Al1[ks] = l; }
                    }
                }
            }
            __syncthreads();
        }
    }
    for (int i = tid; i < BINS; i += 512) normsp[i] = cbnf[q * BINS + i];
    __syncthreads();   // resf dead; BBUF takes over the union

    // ---- staging assignment: wave stages (sbw, splane, ks4..ks4+3), 4 KB/wave/iter
    const int sbw = w & 1, splane = (w >> 1) & 1, sks4 = (w >> 2) * 4;
    const unsigned short* sbase = (splane ? bfl : bfh);

    // prologue: stage nt=0 -> buf0, nt=1 -> buf1
    #pragma unroll
    for (int pnt = 0; pnt < 2; ++pnt) {
        const int nta = (pnt + rot) & 31;
        const unsigned short* srcp =
            sbase + ((size_t)q * 512 + (sbw * 32 + nta) * 8 + sks4) * 512 + lane * 8;
        const int dstb = pnt * 32768 + sbw * 16384 + splane * 8192 + sks4 * 1024;
        #pragma unroll
        for (int i = 0; i < 4; ++i) STAGE16(srcp + i * 512, dstb + i * 1024);
    }

    // ---- scan loop: 32 x (16 bins per bin-wave) with counted-vmcnt double buffer
    float bv1[8], bv2[8]; int bi1[8];
    #pragma unroll
    for (int s = 0; s < 8; ++s) { bv1[s] = 3.4e38f; bv2[s] = 3.4e38f; bi1[s] = 0; }

    #pragma unroll 1
    for (int nt = 0; nt < 32; ++nt) {
        if (nt == 31) { asm volatile("s_waitcnt vmcnt(0)" ::: "memory"); }
        else          { asm volatile("s_waitcnt vmcnt(4)" ::: "memory"); }
        __builtin_amdgcn_s_barrier();
        asm volatile("" ::: "memory");

        const int ntr = (nt + rot) & 31;
        const int cur = nt & 1;
        const char* bb = smc + cur * 32768 + bw * 16384;

        float4v a00 = {0,0,0,0}, a01 = {0,0,0,0}, a10 = {0,0,0,0}, a11 = {0,0,0,0};
        #pragma unroll
        for (int ks = 0; ks < 8; ++ks) {
            const short8v Bh = *(const short8v*)(bb + ks * 1024 + lane * 16);
            const short8v Bl = *(const short8v*)(bb + 8192 + ks * 1024 + lane * 16);
            float4v& c0 = (ks & 1) ? a01 : a00;
            float4v& c1 = (ks & 1) ? a11 : a10;
            c0 = __builtin_amdgcn_mfma_f32_16x16x32_bf16(Al0[ks], Bh, c0, 0, 0, 0);
            c1 = __builtin_amdgcn_mfma_f32_16x16x32_bf16(Al1[ks], Bh, c1, 0, 0, 0);
            c0 = __builtin_amdgcn_mfma_f32_16x16x32_bf16(Ah0[ks], Bl, c0, 0, 0, 0);
            c1 = __builtin_amdgcn_mfma_f32_16x16x32_bf16(Ah1[ks], Bl, c1, 0, 0, 0);
            c0 = __builtin_amdgcn_mfma_f32_16x16x32_bf16(Ah0[ks], Bh, c0, 0, 0, 0);
            c1 = __builtin_amdgcn_mfma_f32_16x16x32_bf16(Ah1[ks], Bh, c1, 0, 0, 0);
        }

        const int binb = bw * 512 + ntr * 16 + col;
        const float qn = normsp[binb];
        #pragma unroll
        for (int r = 0; r < 4; ++r) {
            const float s0 = fmaf(-2.0f, a00[r] + a01[r], qn);
            if (s0 < bv1[r]) { bv2[r] = bv1[r]; bv1[r] = s0; bi1[r] = binb; }
            else if (s0 < bv2[r]) bv2[r] = s0;
            const float s1 = fmaf(-2.0f, a10[r] + a11[r], qn);
            if (s1 < bv1[4+r]) { bv2[4+r] = bv1[4+r]; bv1[4+r] = s1; bi1[4+r] = binb; }
            else if (s1 < bv2[4+r]) bv2[4+r] = s1;
        }

        __builtin_amdgcn_s_barrier();
        asm volatile("" ::: "memory");
        if (nt <= 29) {
            const int nta = (nt + 2 + rot) & 31;
            const unsigned short* srcp =
                sbase + ((size_t)q * 512 + (sbw * 32 + nta) * 8 + sks4) * 512 + lane * 8;
            const int dstb = cur * 32768 + sbw * 16384 + splane * 8192 + sks4 * 1024;
            #pragma unroll
            for (int i = 0; i < 4; ++i) STAGE16(srcp + i * 512, dstb + i * 1024);
        }
    }
    __syncthreads();

    // ---- top-2 merge across the 16 cols, index tiebreak
    #pragma unroll
    for (int off = 1; off <= 8; off <<= 1) {
        #pragma unroll
        for (int sl = 0; sl < 8; ++sl) {
            const float ov1 = __shfl_xor(bv1[sl], off, 64);
            const float ov2 = __shfl_xor(bv2[sl], off, 64);
            const int   oi  = __shfl_xor(bi1[sl], off, 64);
            if (ov1 < bv1[sl] || (ov1 == bv1[sl] && oi < bi1[sl])) {
                bv2[sl] = fminf(bv1[sl], ov2); bv1[sl] = ov1; bi1[sl] = oi;
            } else {
                bv2[sl] = fminf(bv2[sl], ov1);
            }
        }
    }
    if (col == 0) {
        const int tw = w >> 1;
        #pragma unroll
        for (int mt = 0; mt < 2; ++mt)
            #pragma unroll
            for (int r = 0; r < 4; ++r) {
                const int tk = tw * 32 + mt * 16 + rgrp * 4 + r;
                const int sl = mt * 4 + r;
                mg1[tk * 2 + bw] = bv1[sl];
                mg2[tk * 2 + bw] = bv2[sl];
                mgi[tk * 2 + bw] = bi1[sl];
            }
    }
    __syncthreads();

    if (tid < 128) {
        float g1 = mg1[tid*2], g2 = mg2[tid*2]; int gi = mgi[tid*2];
        const float v1 = mg1[tid*2+1], v2 = mg2[tid*2+1];
        const int   i1 = mgi[tid*2+1];
        if (v1 < g1 || (v1 == g1 && i1 < gi)) { g2 = fminf(g1, v2); g1 = v1; gi = i1; }
        else g2 = fminf(g2, v1);
        idxsL[tid]  = gi;
        flagsL[tid] = (g2 - g1 < EPS) ? 1 : 0;
    }
    __syncthreads();

    // ---- exact f64 full-scan fallback for near-tie tokens (rare)
    const float* cbq = cb + (size_t)q * BINS * D;
    #pragma unroll 1
    for (int tk2 = 0; tk2 < 128; ++tk2) {
        if (!flagsL[tk2]) continue;                  // uniform branch (LDS)
        if (tid < 256) rstage[tid] = rs[(size_t)tid * T + tk2];
        __syncthreads();
        double bb2 = 1e300; int bbi = 0;
        #pragma unroll 1
        for (int jj = 0; jj < 2; ++jj) {
            const int bin = tid + 512 * jj;          // ascending -> lowest-idx kept
            const float* crow = cbq + (size_t)bin * D;
            double a = 0.0;
            for (int d = 0; d < D; d += 4) {
                const float4 rv = *(const float4*)&rstage[d];
                const float4 cv = *(const float4*)&crow[d];
                a = fma((double)rv.x, (double)cv.x, a);
                a = fma((double)rv.y, (double)cv.y, a);
                a = fma((double)rv.z, (double)cv.z, a);
                a = fma((double)rv.w, (double)cv.w, a);
            }
            const double s = fma(-2.0, a, cbn[q * BINS + bin]);
            if (s < bb2) { bb2 = s; bbi = bin; }
        }
        redv[tid] = bb2; redi[tid] = bbi;
        __syncthreads();
        for (int s2 = 256; s2 >= 1; s2 >>= 1) {
            if (tid < s2) {
                const double ov = redv[tid + s2]; const int oi = redi[tid + s2];
                if (ov < redv[tid] || (ov == redv[tid] && oi < redi[tid])) {
                    redv[tid] = ov; redi[tid] = oi;
                }
            }
            __syncthreads();
        }
        if (tid == 0) idxsL[tk2] = redi[0];
        __syncthreads();
    }

    // ---- codes
    if (tid < 128)
        out[OFF_C + (size_t)q * B * T + (size_t)b * T + t0 + tid] = (float)idxsL[tid];

    // ---- faithful f32 straight-through update (coalesced) + loss
    double lacc = 0.0;
    #pragma unroll 1
    for (int it = 0; it < 64; ++it) {
        const int lin = it * 512 + tid;
        const int tk = lin & 127, d = lin >> 7;
        const float r  = __builtin_nontemporal_load(&rs[(size_t)d * T + tk]);
        const float cv = cbq[(size_t)idxsL[tk] * D + d];
        const float e   = cv - r;
        const float qst = r + e;
        const float dd  = qst - r;
        lacc = fma((double)dd, (double)dd, lacc);
        __builtin_nontemporal_store(r - qst, &rd[(size_t)d * T + tk]);
    }

    // ---- deterministic per-block loss partial
    redv[tid] = lacc;
    __syncthreads();
    for (int s2 = 256; s2 >= 1; s2 >>= 1) {
        if (tid < s2) redv[tid] += redv[tid + s2];
        __syncthreads();
    }
    if (tid == 0) lpart[(size_t)q * 512 + bid] = redv[0];
}

// ---------------- final: quantized = x - res, in place on out[0:B*D*T) ----------
__global__ __launch_bounds__(256) void final_sub(const float* __restrict__ x,
                                                 float* __restrict__ o)
{
    const size_t i = ((size_t)blockIdx.x * 256 + threadIdx.x) * 4;
    const float4v xv = __builtin_nontemporal_load((const float4v*)(x + i));
    const float4v ov = __builtin_nontemporal_load((const float4v*)(o + i));
    const float4v r = xv - ov;
    __builtin_nontemporal_store(r, (float4v*)(o + i));
}

// ---------------- OLD PATH (R2, known-good) kept as ws-size fallback ----------------
#define OTOK 32
#define ORS 260
__global__ __launch_bounds__(256, 3) void rvq_main_old(
    const float* __restrict__ x, const float* __restrict__ cb,
    const double* __restrict__ cbn, const float* __restrict__ cbnf,
    float* __restrict__ out, double* __restrict__ lpart)
{
    __shared__ float  res[OTOK][ORS];
    __shared__ float  bv1s[OTOK][16];
    __shared__ float  bv2s[OTOK][16];
    __shared__ int    bi1s[OTOK][16];
    __shared__ int    idxs[OTOK];
    __shared__ int    flags[OTOK];
    __shared__ double fbv[256];
    __shared__ int    fbi[256];

    const int tid = threadIdx.x;
    const int bid = blockIdx.x;
    const int b  = bid >> 7;
    const int t0 = (bid & 127) * OTOK;

    const float* xb = x + (size_t)b * D * T + t0;
    #pragma unroll
    for (int it = 0; it < 32; ++it) {
        const int d  = it * 8 + (tid >> 5);
        const int tk = tid & 31;
        res[tk][d] = xb[(size_t)d * T + tk];
    }
    __syncthreads();

    float qreg[32];
    #pragma unroll
    for (int i = 0; i < 32; ++i) qreg[i] = 0.0f;

    const int tg = tid & 15;
    const int bg = tid >> 4;
    const int tku = tid >> 3;
    const int d0u = (tid & 7) * 32;
    double lacc = 0.0;

    for (int q = 0; q < NQ; ++q) {
        const float*  cbq = cb   + (size_t)q * BINS * D;
        const float*  cnf = cbnf + (size_t)q * BINS;
        const double* cnd = cbn  + (size_t)q * BINS;

        float bvA = 3.4e38f, bvA2 = 3.4e38f;  int biA = 0;
        float bvB = 3.4e38f, bvB2 = 3.4e38f;  int biB = 0;

        for (int iter = 0; iter < 8; ++iter) {
            const int binbase = iter * 128 + bg * 8;
            float a0[8], a1[8];
            #pragma unroll
            for (int j = 0; j < 8; ++j) { a0[j] = 0.0f; a1[j] = 0.0f; }
            for (int d = 0; d < D; d += 4) {
                const float4 r0 = *(const float4*)&res[tg][d];
                const float4 r1 = *(const float4*)&res[tg + 16][d];
                #pragma unroll
                for (int j = 0; j < 8; ++j) {
                    const float4 c = *(const float4*)&cbq[(size_t)(binbase + j) * D + d];
                    a0[j] = fmaf(r0.x, c.x, a0[j]); a0[j] = fmaf(r0.y, c.y, a0[j]);
                    a0[j] = fmaf(r0.z, c.z, a0[j]); a0[j] = fmaf(r0.w, c.w, a0[j]);
                    a1[j] = fmaf(r1.x, c.x, a1[j]); a1[j] = fmaf(r1.y, c.y, a1[j]);
                    a1[j] = fmaf(r1.z, c.z, a1[j]); a1[j] = fmaf(r1.w, c.w, a1[j]);
                }
            }
            #pragma unroll
            for (int j = 0; j < 8; ++j) {
                const int bin = binbase + j;
                const float qn = cnf[bin];
                const float s0 = fmaf(-2.0f, a0[j], qn);
                const float s1 = fmaf(-2.0f, a1[j], qn);
                if (s0 < bvA) { bvA2 = bvA; bvA = s0; biA = bin; }
                else if (s0 < bvA2) { bvA2 = s0; }
                if (s1 < bvB) { bvB2 = bvB; bvB = s1; biB = bin; }
                else if (s1 < bvB2) { bvB2 = s1; }
            }
        }
        bv1s[tg][bg]      = bvA;  bv2s[tg][bg]      = bvA2;  bi1s[tg][bg]      = biA;
        bv1s[tg + 16][bg] = bvB;  bv2s[tg + 16][bg] = bvB2;  bi1s[tg + 16][bg] = biB;
        __syncthreads();

        if (tid < OTOK) {
            float g1 = bv1s[tid][0], g2 = bv2s[tid][0];
            int   gi = bi1s[tid][0];
            #pragma unroll
            for (int g = 1; g < 16; ++g) {
                const float v1 = bv1s[tid][g];
                const float v2 = bv2s[tid][g];
                const int   i1 = bi1s[tid][g];
                if (v1 < g1 || (v1 == g1 && i1 < gi)) { g2 = fminf(g1, v2); g1 = v1; gi = i1; }
                else g2 = fminf(g2, v1);
            }
            idxs[tid]  = gi;
            flags[tid] = (g2 - g1 < 0.02f) ? 1 : 0;
        }
        __syncthreads();

        for (int tok = 0; tok < OTOK; ++tok) {
            if (!flags[tok]) continue;
            double bb = 1e300; int bbi = 0;
            #pragma unroll
            for (int jj = 0; jj < 4; ++jj) {
                const int bin = tid + 256 * jj;
                const float* crow = cbq + (size_t)bin * D;
                double a = 0.0;
                for (int d = 0; d < D; d += 4) {
                    const float4 r = *(const float4*)&res[tok][d];
                    const float4 c = *(const float4*)&crow[d];
                    a = fma((double)r.x, (double)c.x, a);
                    a = fma((double)r.y, (double)c.y, a);
                    a = fma((double)r.z, (double)c.z, a);
                    a = fma((double)r.w, (double)c.w, a);
                }
                const double s = fma(-2.0, a, cnd[bin]);
                if (s < bb) { bb = s; bbi = bin; }
            }
            fbv[tid] = bb; fbi[tid] = bbi;
            __syncthreads();
            for (int s2 = 128; s2 >= 1; s2 >>= 1) {
                if (tid < s2) {
                    const double ov = fbv[tid + s2]; const int oi = fbi[tid + s2];
                    const double mv = fbv[tid];      const int mi = fbi[tid];
                    if (ov < mv || (ov == mv && oi < mi)) { fbv[tid] = ov; fbi[tid] = oi; }
                }
                __syncthreads();
            }
            if (tid == 0) idxs[tok] = fbi[0];
            __syncthreads();
        }

        if (tid < OTOK)
            out[OFF_C + (size_t)q * B * T + (size_t)b * T + t0 + tid] = (float)idxs[tid];

        const float* crow = cbq + (size_t)idxs[tku] * D;
        #pragma unroll
        for (int i = 0; i < 8; ++i) {
            const int d = d0u + i * 4;
            const float4 qv = *(const float4*)&crow[d];
            float4 r = *(float4*)&res[tku][d];
            float e, qst, dd;
            e = qv.x - r.x; qst = r.x + e; dd = qst - r.x;
            lacc = fma((double)dd, (double)dd, lacc); qreg[i*4+0] += qst; r.x = r.x - qst;
            e = qv.y - r.y; qst = r.y + e; dd = qst - r.y;
            lacc = fma((double)dd, (double)dd, lacc); qreg[i*4+1] += qst; r.y = r.y - qst;
            e = qv.z - r.z; qst = r.z + e; dd = qst - r.z;
            lacc = fma((double)dd, (double)dd, lacc); qreg[i*4+2] += qst; r.z = r.z - qst;
            e = qv.w - r.w; qst = r.w + e; dd = qst - r.w;
            lacc = fma((double)dd, (double)dd, lacc); qreg[i*4+3] += qst; r.w = r.w - qst;
            *(float4*)&res[tku][d] = r;
        }
        __syncthreads();
    }

    #pragma unroll
    for (int i = 0; i < 8; ++i)
        *(float4*)&res[tku][d0u + i * 4] = *(float4*)&qreg[i * 4];
    __syncthreads();
    #pragma unroll
    for (int it = 0; it < 32; ++it) {
        const int d  = it * 8 + (tid >> 5);
        const int tk = tid & 31;
        out[(size_t)b * D * T + (size_t)d * T + t0 + tk] = res[tk][d];
    }

    fbv[tid] = lacc;
    __syncthreads();
    for (int s2 = 128; s2 >= 1; s2 >>= 1) {
        if (tid < s2) fbv[tid] += fbv[tid + s2];
        __syncthreads();
    }
    if (tid == 0) lpart[bid] = fbv[0];
}

// ---------------- finalize: loss mean + bandwidth scalar ----------------
__global__ __launch_bounds__(256) void finalize_kernel(
    const double* __restrict__ lpart, int nblk,
    const int* __restrict__ srp, float* __restrict__ out)
{
    __shared__ double sh[256];
    double a = 0.0;
    for (int i = threadIdx.x; i < nblk; i += 256) a += lpart[i];
    sh[threadIdx.x] = a;
    __syncthreads();
    for (int s = 128; s >= 1; s >>= 1) {
        if (threadIdx.x < s) sh[threadIdx.x] += sh[threadIdx.x + s];
        __syncthreads();
    }
    if (threadIdx.x == 0) {
        out[OFF_L]  = (float)(sh[0] / ((double)NQ * B * T * D));
        out[OFF_BW] = (float)((double)NQ * 10.0 * (double)srp[0] / 1000.0);
    }
}

extern "C" void kernel_launch(void* const* d_in, const int* in_sizes, int n_in,
                              void* d_out, int out_size, void* d_ws, size_t ws_size,
                              hipStream_t stream)
{
    const float* x  = (const float*)d_in[0];
    const float* cb = (const float*)d_in[1];
    const int*   sr = (const int*)d_in[2];
    float* out = (float*)d_out;

    // ws layout: cbn f64[8192] @0 (65536) | cbnf f32[8192] @65536 (32768)
    //            lpart f64 @98304 (65536) | bfh @163840 (4 MiB) | bfl @4358144
    //            total 8552448 B
    double* cbn   = (double*)d_ws;
    float*  cbnf  = (float*)((char*)d_ws + 65536);
    double* lpart = (double*)((char*)d_ws + 98304);
    unsigned short* bfh = (unsigned short*)((char*)d_ws + 163840);
    unsigned short* bfl = (unsigned short*)((char*)d_ws + 4358144);

    hipLaunchKernelGGL(cbnorm_kernel, dim3(NQ * BINS / 4), dim3(256), 0, stream, cb, cbn, cbnf);

    if (ws_size >= (size_t)8552448) {
        hipLaunchKernelGGL(prep_bfrag, dim3(1024), dim3(256), 0, stream, cb, bfh, bfl);
        float* resb = out;   // quantized section doubles as residual buffer
        for (int q = 0; q < NQ; ++q) {
            hipLaunchKernelGGL(rvq_scan, dim3(B * (T / 128)), dim3(512), 0, stream,
                               (q == 0 ? x : (const float*)resb), resb, cb, cbn, cbnf,
                               bfh, bfl, out, lpart, q);
        }
        hipLaunchKernelGGL(final_sub, dim3((B * D * T) / 1024), dim3(256), 0, stream, x, resb);
        hipLaunchKernelGGL(finalize_kernel, dim3(1), dim3(256), 0, stream,
                           lpart, NQ * 512, sr, out);
    } else {
        hipLaunchKernelGGL(rvq_main_old, dim3(B * (T / OTOK)), dim3(256), 0, stream,
                           x, cb, cbn, cbnf, out, lpart);
        hipLaunchKernelGGL(finalize_kernel, dim3(1), dim3(256), 0, stream,
                           lpart, B * (T / OTOK), sr, out);
    }
}

// Round 8
// 2227.142 us; speedup vs baseline: 2.8700x; 1.2184x over previous
//
#include <hip/hip_runtime.h>

#define B 16
#define D 256
#define T 4096
#define NQ 8
#define BINS 1024
#define EPS 0.008f

#define OFF_C  ((size_t)B * D * T)            // quantized elems = 16777216
#define OFF_BW (OFF_C + (size_t)NQ * B * T)   // + codes 524288 -> 17301504
#define OFF_L  (OFF_BW + 1)

typedef __attribute__((ext_vector_type(8))) short short8v;
typedef __attribute__((ext_vector_type(4))) float float4v;

// ---- LDS map (bytes) for rvq_scan (512 threads, 64 tokens, 2 blocks/CU) ----
#define BBUF   0        // 2 x 32768 B double buffer (union with RESF: 64*257*4=65792)
#define RESF   0
#define NORMS  65792    // f32[1024]  -> 69888
#define MG1    69888    // f32[128]   -> 70400
#define MG2    70400    // f32[128]   -> 70912
#define MGI    70912    // i32[128]   -> 71424
#define IDXS   71424    // i32[64]    -> 71680
#define FLAGS  71680    // i32[64]    -> 71936
#define G1L    71936    // f32[64]    -> 72192
#define RSTG   72192    // f32[256]   -> 73216
#define REDV   73216    // f64[512]   -> 77312
#define REDI   77312    // i32[512]   -> 79360
#define SMTOT  79360    // x2 = 158720 <= 163840 -> 2 blocks/CU

#define STAGE16(gp, loff) \
  __builtin_amdgcn_global_load_lds( \
      (const __attribute__((address_space(1))) unsigned int*)(gp), \
      (__attribute__((address_space(3))) unsigned int*)(smc + (loff)), 16, 0, 0)

__device__ __forceinline__ unsigned short f2bf(float f) {
    unsigned u = __float_as_uint(f);
    unsigned r = (u + 0x7fffu + ((u >> 16) & 1u)) >> 16;   // RNE
    return (unsigned short)r;
}
__device__ __forceinline__ float bf2f(unsigned short h) {
    return __uint_as_float(((unsigned)h) << 16);
}

// ---------------- codebook norms: f64 (exact fallback) + f32 (scan) ----------------
__global__ __launch_bounds__(256) void cbnorm_kernel(const float* __restrict__ cb,
                                                     double* __restrict__ cbn,
                                                     float* __restrict__ cbnf)
{
    const int wave = threadIdx.x >> 6;
    const int lane = threadIdx.x & 63;
    const int bin = blockIdx.x * 4 + wave;          // 0..8191 (q*1024+k)
    const float4 v = *(const float4*)&cb[(size_t)bin * D + lane * 4];
    double a = (double)v.x * v.x + (double)v.y * v.y
             + (double)v.z * v.z + (double)v.w * v.w;
    #pragma unroll
    for (int off = 32; off >= 1; off >>= 1)
        a += __shfl_xor(a, off, 64);
    if (lane == 0) { cbn[bin] = a; cbnf[bin] = (float)a; }
}

// ---------------- prep: codebook -> bf16 hi/lo planes in MFMA-B-fragment order ----
// frag c = q*512 + ntg*8 + ks ; lane l, j -> B[k=ks*32+(l>>4)*8+j][n=ntg*16+(l&15)]
__global__ __launch_bounds__(256) void prep_bfrag(const float* __restrict__ cb,
                                                  unsigned short* __restrict__ bfh,
                                                  unsigned short* __restrict__ bfl)
{
    const int c = blockIdx.x * 4 + (threadIdx.x >> 6);   // 0..4095
    const int lane = threadIdx.x & 63;
    const int q = c >> 9, ntg = (c >> 3) & 63, ks = c & 7;
    const float* src = cb + ((size_t)q * BINS + ntg * 16 + (lane & 15)) * D
                         + ks * 32 + (lane >> 4) * 8;
    short8v h, l;
    #pragma unroll
    for (int j = 0; j < 8; ++j) {
        const float v = src[j];
        const unsigned short hh = f2bf(v);
        h[j] = (short)hh;
        l[j] = (short)f2bf(v - bf2f(hh));
    }
    const size_t off = ((size_t)c * 64 + lane) * 8;
    *(short8v*)(bfh + off) = h;
    *(short8v*)(bfl + off) = l;
}

// ---------------- per-stage scan+update (one launch per q) ----------------
// 512 threads, 64 tokens/block, 8 waves: tw = w>>1 (16 tokens each), bw = w&1.
// A (16 tok x 256 K, hi+lo) in 64 regs/thread; B via LDS double buffer + counted vmcnt.
__global__ __launch_bounds__(512, 4) void rvq_scan(
    const float* __restrict__ rsrc, float* __restrict__ rdst,
    const float* __restrict__ cb,
    const double* __restrict__ cbn, const float* __restrict__ cbnf,
    const unsigned short* __restrict__ bfh, const unsigned short* __restrict__ bfl,
    float* __restrict__ out, double* __restrict__ lpart, int q)
{
    __shared__ __align__(16) char smem[SMTOT];
    char*   smc    = smem;
    float*  resf   = (float*)(smem + RESF);
    float*  normsp = (float*)(smem + NORMS);
    float*  mg1    = (float*)(smem + MG1);
    float*  mg2    = (float*)(smem + MG2);
    int*    mgi    = (int*)(smem + MGI);
    int*    idxsL  = (int*)(smem + IDXS);
    int*    flagsL = (int*)(smem + FLAGS);
    float*  g1L    = (float*)(smem + G1L);
    float*  rstage = (float*)(smem + RSTG);
    double* redv   = (double*)(smem + REDV);
    int*    redi   = (int*)(smem + REDI);

    const int tid  = threadIdx.x;
    const int bid  = blockIdx.x;
    const int b    = bid >> 6;            // T/64 = 64 tiles per batch
    const int t0   = (bid & 63) * 64;
    const int w    = tid >> 6;            // 0..7
    const int lane = tid & 63;
    const int col  = lane & 15;
    const int rgrp = lane >> 4;
    const int tw   = w >> 1;              // token group (16 tokens)
    const int bw   = w & 1;               // bin half
    const int rot  = (bid * 5) & 31;      // per-block bin-group rotation (L2 spread)

    const float* rs = rsrc + (size_t)b * D * T + t0;
    float*       rd = rdst + (size_t)b * D * T + t0;

    // ---- 1. stage residual tile global->LDS (coalesced along t, transpose)
    #pragma unroll 1
    for (int it = 0; it < 32; ++it) {
        const int lin = it * 512 + tid;
        resf[(lin & 63) * 257 + (lin >> 6)] =
            __builtin_nontemporal_load(&rs[(size_t)(lin >> 6) * T + (lin & 63)]);
    }
    __syncthreads();

    // ---- 2. A-fragments in registers: 16 tokens/wave, K=256, hi+lo
    short8v Ah[8], Al[8];
    {
        const int tokA = tw * 16 + col;
        #pragma unroll
        for (int ks = 0; ks < 8; ++ks) {
            short8v h, l;
            #pragma unroll
            for (int j = 0; j < 8; ++j) {
                const float v = resf[tokA * 257 + ks * 32 + rgrp * 8 + j];
                const unsigned short hh = f2bf(v);
                h[j] = (short)hh;
                l[j] = (short)f2bf(v - bf2f(hh));
            }
            Ah[ks] = h; Al[ks] = l;
        }
    }
    for (int i = tid; i < BINS; i += 512) normsp[i] = cbnf[q * BINS + i];
    __syncthreads();   // resf dead; BBUF takes over the union

    // ---- staging assignment: wave stages (sbw, splane, ks4..ks4+3), 4 KB/wave/iter
    const int sbw = w & 1, splane = (w >> 1) & 1, sks4 = (w >> 2) * 4;
    const unsigned short* sbase = (splane ? bfl : bfh);

    // prologue: stage nt=0 -> buf0, nt=1 -> buf1
    #pragma unroll
    for (int pnt = 0; pnt < 2; ++pnt) {
        const int nta = (pnt + rot) & 31;
        const unsigned short* srcp =
            sbase + ((size_t)q * 512 + (sbw * 32 + nta) * 8 + sks4) * 512 + lane * 8;
        const int dstb = pnt * 32768 + sbw * 16384 + splane * 8192 + sks4 * 1024;
        #pragma unroll
        for (int i = 0; i < 4; ++i) STAGE16(srcp + i * 512, dstb + i * 1024);
    }

    // ---- 3. scan loop: 32 x (16 bins per bin-wave), counted-vmcnt double buffer
    float bv1[4], bv2[4]; int bi1[4];
    #pragma unroll
    for (int s = 0; s < 4; ++s) { bv1[s] = 3.4e38f; bv2[s] = 3.4e38f; bi1[s] = 0; }

    #pragma unroll 1
    for (int nt = 0; nt < 32; ++nt) {
        if (nt == 31) { asm volatile("s_waitcnt vmcnt(0)" ::: "memory"); }
        else          { asm volatile("s_waitcnt vmcnt(4)" ::: "memory"); }
        __builtin_amdgcn_s_barrier();
        asm volatile("" ::: "memory");

        const int ntr = (nt + rot) & 31;
        const int cur = nt & 1;
        const char* bb = smc + cur * 32768 + bw * 16384;

        float4v a0 = {0,0,0,0}, a1 = {0,0,0,0};
        #pragma unroll
        for (int ks = 0; ks < 8; ++ks) {
            const short8v Bh = *(const short8v*)(bb + ks * 1024 + lane * 16);
            const short8v Bl = *(const short8v*)(bb + 8192 + ks * 1024 + lane * 16);
            float4v& c = (ks & 1) ? a1 : a0;
            c = __builtin_amdgcn_mfma_f32_16x16x32_bf16(Al[ks], Bh, c, 0, 0, 0);
            c = __builtin_amdgcn_mfma_f32_16x16x32_bf16(Ah[ks], Bl, c, 0, 0, 0);
            c = __builtin_amdgcn_mfma_f32_16x16x32_bf16(Ah[ks], Bh, c, 0, 0, 0);
        }

        const int binb = bw * 512 + ntr * 16 + col;
        const float qn = normsp[binb];
        #pragma unroll
        for (int r = 0; r < 4; ++r) {
            const float s0 = fmaf(-2.0f, a0[r] + a1[r], qn);
            if (s0 < bv1[r]) { bv2[r] = bv1[r]; bv1[r] = s0; bi1[r] = binb; }
            else if (s0 < bv2[r]) bv2[r] = s0;
        }

        __builtin_amdgcn_s_barrier();
        asm volatile("" ::: "memory");
        if (nt <= 29) {
            const int nta = (nt + 2 + rot) & 31;
            const unsigned short* srcp =
                sbase + ((size_t)q * 512 + (sbw * 32 + nta) * 8 + sks4) * 512 + lane * 8;
            const int dstb = cur * 32768 + sbw * 16384 + splane * 8192 + sks4 * 1024;
            #pragma unroll
            for (int i = 0; i < 4; ++i) STAGE16(srcp + i * 512, dstb + i * 1024);
        }
    }
    __syncthreads();

    // ---- 4. top-2 merge across the 16 cols, index tiebreak
    #pragma unroll
    for (int off = 1; off <= 8; off <<= 1) {
        #pragma unroll
        for (int sl = 0; sl < 4; ++sl) {
            const float ov1 = __shfl_xor(bv1[sl], off, 64);
            const float ov2 = __shfl_xor(bv2[sl], off, 64);
            const int   oi  = __shfl_xor(bi1[sl], off, 64);
            if (ov1 < bv1[sl] || (ov1 == bv1[sl] && oi < bi1[sl])) {
                bv2[sl] = fminf(bv1[sl], ov2); bv1[sl] = ov1; bi1[sl] = oi;
            } else {
                bv2[sl] = fminf(bv2[sl], ov1);
            }
        }
    }
    if (col == 0) {
        #pragma unroll
        for (int r = 0; r < 4; ++r) {
            const int tk = tw * 16 + rgrp * 4 + r;
            mg1[tk * 2 + bw] = bv1[r];
            mg2[tk * 2 + bw] = bv2[r];
            mgi[tk * 2 + bw] = bi1[r];
        }
    }
    __syncthreads();

    if (tid < 64) {
        float g1 = mg1[tid*2], g2 = mg2[tid*2]; int gi = mgi[tid*2];
        const float v1 = mg1[tid*2+1], v2 = mg2[tid*2+1];
        const int   i1 = mgi[tid*2+1];
        if (v1 < g1 || (v1 == g1 && i1 < gi)) { g2 = fminf(g1, v2); g1 = v1; gi = i1; }
        else g2 = fminf(g2, v1);
        idxsL[tid]  = gi;
        g1L[tid]    = g1;
        flagsL[tid] = (g2 - g1 < EPS) ? 1 : 0;
    }
    __syncthreads();

    // ---- 5. exact fallback for near-tie tokens: f32 prefilter + f64 only for
    //         bins within g1 + 0.0065 (covers scan err ~2e-3 + rescan err ~1e-3)
    const float* cbq = cb + (size_t)q * BINS * D;
    #pragma unroll 1
    for (int tk2 = 0; tk2 < 64; ++tk2) {
        if (!flagsL[tk2]) continue;                  // uniform branch (LDS)
        if (tid < 256) rstage[tid] = rs[(size_t)tid * T + tk2];
        __syncthreads();
        const float thr = g1L[tk2] + 0.0065f;
        double bb2 = 1e300; int bbi = 0x7fffffff;
        #pragma unroll 1
        for (int jj = 0; jj < 2; ++jj) {
            const int bin = tid + 512 * jj;          // ascending -> lowest-idx kept
            const float* crow = cbq + (size_t)bin * D;
            float f0 = 0.f, f1 = 0.f, f2 = 0.f, f3 = 0.f;
            for (int d = 0; d < D; d += 4) {
                const float4 rv = *(const float4*)&rstage[d];
                const float4 cv = *(const float4*)&crow[d];
                f0 = fmaf(rv.x, cv.x, f0); f1 = fmaf(rv.y, cv.y, f1);
                f2 = fmaf(rv.z, cv.z, f2); f3 = fmaf(rv.w, cv.w, f3);
            }
            const float sf = fmaf(-2.0f, (f0 + f1) + (f2 + f3), normsp[bin]);
            if (sf <= thr) {                         // rare: ~1-3 bins per token
                double a = 0.0;
                for (int d = 0; d < D; d += 4) {
                    const float4 rv = *(const float4*)&rstage[d];
                    const float4 cv = *(const float4*)&crow[d];
                    a = fma((double)rv.x, (double)cv.x, a);
                    a = fma((double)rv.y, (double)cv.y, a);
                    a = fma((double)rv.z, (double)cv.z, a);
                    a = fma((double)rv.w, (double)cv.w, a);
                }
                const double s = fma(-2.0, a, cbn[q * BINS + bin]);
                if (s < bb2) { bb2 = s; bbi = bin; }
            }
        }
        redv[tid] = bb2; redi[tid] = bbi;
        __syncthreads();
        for (int s2 = 256; s2 >= 1; s2 >>= 1) {
            if (tid < s2) {
                const double ov = redv[tid + s2]; const int oi = redi[tid + s2];
                if (ov < redv[tid] || (ov == redv[tid] && oi < redi[tid])) {
                    redv[tid] = ov; redi[tid] = oi;
                }
            }
            __syncthreads();
        }
        if (tid == 0) idxsL[tk2] = redi[0];
        __syncthreads();
    }

    // ---- 6. codes
    if (tid < 64)
        out[OFF_C + (size_t)q * B * T + (size_t)b * T + t0 + tid] = (float)idxsL[tid];

    // ---- 7. faithful f32 straight-through update (coalesced) + loss
    double lacc = 0.0;
    #pragma unroll 1
    for (int it = 0; it < 32; ++it) {
        const int lin = it * 512 + tid;
        const int tk = lin & 63, d = lin >> 6;
        const float r  = __builtin_nontemporal_load(&rs[(size_t)d * T + tk]);
        const float cv = cbq[(size_t)idxsL[tk] * D + d];
        const float e   = cv - r;
        const float qst = r + e;
        const float dd  = qst - r;
        lacc = fma((double)dd, (double)dd, lacc);
        __builtin_nontemporal_store(r - qst, &rd[(size_t)d * T + tk]);
    }

    // ---- 8. deterministic per-block loss partial
    redv[tid] = lacc;
    __syncthreads();
    for (int s2 = 256; s2 >= 1; s2 >>= 1) {
        if (tid < s2) redv[tid] += redv[tid + s2];
        __syncthreads();
    }
    if (tid == 0) lpart[(size_t)q * 1024 + bid] = redv[0];
}

// ---------------- final: quantized = x - res, in place on out[0:B*D*T) ----------
__global__ __launch_bounds__(256) void final_sub(const float* __restrict__ x,
                                                 float* __restrict__ o)
{
    const size_t i = ((size_t)blockIdx.x * 256 + threadIdx.x) * 4;
    const float4v xv = __builtin_nontemporal_load((const float4v*)(x + i));
    const float4v ov = __builtin_nontemporal_load((const float4v*)(o + i));
    const float4v r = xv - ov;
    __builtin_nontemporal_store(r, (float4v*)(o + i));
}

// ---------------- OLD PATH (R2, known-good) kept as ws-size fallback ----------------
#define OTOK 32
#define ORS 260
__global__ __launch_bounds__(256, 3) void rvq_main_old(
    const float* __restrict__ x, const float* __restrict__ cb,
    const double* __restrict__ cbn, const float* __restrict__ cbnf,
    float* __restrict__ out, double* __restrict__ lpart)
{
    __shared__ float  res[OTOK][ORS];
    __shared__ float  bv1s[OTOK][16];
    __shared__ float  bv2s[OTOK][16];
    __shared__ int    bi1s[OTOK][16];
    __shared__ int    idxs[OTOK];
    __shared__ int    flags[OTOK];
    __shared__ double fbv[256];
    __shared__ int    fbi[256];

    const int tid = threadIdx.x;
    const int bid = blockIdx.x;
    const int b  = bid >> 7;
    const int t0 = (bid & 127) * OTOK;

    const float* xb = x + (size_t)b * D * T + t0;
    #pragma unroll
    for (int it = 0; it < 32; ++it) {
        const int d  = it * 8 + (tid >> 5);
        const int tk = tid & 31;
        res[tk][d] = xb[(size_t)d * T + tk];
    }
    __syncthreads();

    float qreg[32];
    #pragma unroll
    for (int i = 0; i < 32; ++i) qreg[i] = 0.0f;

    const int tg = tid & 15;
    const int bg = tid >> 4;
    const int tku = tid >> 3;
    const int d0u = (tid & 7) * 32;
    double lacc = 0.0;

    for (int q = 0; q < NQ; ++q) {
        const float*  cbq = cb   + (size_t)q * BINS * D;
        const float*  cnf = cbnf + (size_t)q * BINS;
        const double* cnd = cbn  + (size_t)q * BINS;

        float bvA = 3.4e38f, bvA2 = 3.4e38f;  int biA = 0;
        float bvB = 3.4e38f, bvB2 = 3.4e38f;  int biB = 0;

        for (int iter = 0; iter < 8; ++iter) {
            const int binbase = iter * 128 + bg * 8;
            float a0[8], a1[8];
            #pragma unroll
            for (int j = 0; j < 8; ++j) { a0[j] = 0.0f; a1[j] = 0.0f; }
            for (int d = 0; d < D; d += 4) {
                const float4 r0 = *(const float4*)&res[tg][d];
                const float4 r1 = *(const float4*)&res[tg + 16][d];
                #pragma unroll
                for (int j = 0; j < 8; ++j) {
                    const float4 c = *(const float4*)&cbq[(size_t)(binbase + j) * D + d];
                    a0[j] = fmaf(r0.x, c.x, a0[j]); a0[j] = fmaf(r0.y, c.y, a0[j]);
                    a0[j] = fmaf(r0.z, c.z, a0[j]); a0[j] = fmaf(r0.w, c.w, a0[j]);
                    a1[j] = fmaf(r1.x, c.x, a1[j]); a1[j] = fmaf(r1.y, c.y, a1[j]);
                    a1[j] = fmaf(r1.z, c.z, a1[j]); a1[j] = fmaf(r1.w, c.w, a1[j]);
                }
            }
            #pragma unroll
            for (int j = 0; j < 8; ++j) {
                const int bin = binbase + j;
                const float qn = cnf[bin];
                const float s0 = fmaf(-2.0f, a0[j], qn);
                const float s1 = fmaf(-2.0f, a1[j], qn);
                if (s0 < bvA) { bvA2 = bvA; bvA = s0; biA = bin; }
                else if (s0 < bvA2) { bvA2 = s0; }
                if (s1 < bvB) { bvB2 = bvB; bvB = s1; biB = bin; }
                else if (s1 < bvB2) { bvB2 = s1; }
            }
        }
        bv1s[tg][bg]      = bvA;  bv2s[tg][bg]      = bvA2;  bi1s[tg][bg]      = biA;
        bv1s[tg + 16][bg] = bvB;  bv2s[tg + 16][bg] = bvB2;  bi1s[tg + 16][bg] = biB;
        __syncthreads();

        if (tid < OTOK) {
            float g1 = bv1s[tid][0], g2 = bv2s[tid][0];
            int   gi = bi1s[tid][0];
            #pragma unroll
            for (int g = 1; g < 16; ++g) {
                const float v1 = bv1s[tid][g];
                const float v2 = bv2s[tid][g];
                const int   i1 = bi1s[tid][g];
                if (v1 < g1 || (v1 == g1 && i1 < gi)) { g2 = fminf(g1, v2); g1 = v1; gi = i1; }
                else g2 = fminf(g2, v1);
            }
            idxs[tid]  = gi;
            flags[tid] = (g2 - g1 < 0.02f) ? 1 : 0;
        }
        __syncthreads();

        for (int tok = 0; tok < OTOK; ++tok) {
            if (!flags[tok]) continue;
            double bb = 1e300; int bbi = 0;
            #pragma unroll
            for (int jj = 0; jj < 4; ++jj) {
                const int bin = tid + 256 * jj;
                const float* crow = cbq + (size_t)bin * D;
                double a = 0.0;
                for (int d = 0; d < D; d += 4) {
                    const float4 r = *(const float4*)&res[tok][d];
                    const float4 c = *(const float4*)&crow[d];
                    a = fma((double)r.x, (double)c.x, a);
                    a = fma((double)r.y, (double)c.y, a);
                    a = fma((double)r.z, (double)c.z, a);
                    a = fma((double)r.w, (double)c.w, a);
                }
                const double s = fma(-2.0, a, cnd[bin]);
                if (s < bb) { bb = s; bbi = bin; }
            }
            fbv[tid] = bb; fbi[tid] = bbi;
            __syncthreads();
            for (int s2 = 128; s2 >= 1; s2 >>= 1) {
                if (tid < s2) {
                    const double ov = fbv[tid + s2]; const int oi = fbi[tid + s2];
                    const double mv = fbv[tid];      const int mi = fbi[tid];
                    if (ov < mv || (ov == mv && oi < mi)) { fbv[tid] = ov; fbi[tid] = oi; }
                }
                __syncthreads();
            }
            if (tid == 0) idxs[tok] = fbi[0];
            __syncthreads();
        }

        if (tid < OTOK)
            out[OFF_C + (size_t)q * B * T + (size_t)b * T + t0 + tid] = (float)idxs[tid];

        const float* crow = cbq + (size_t)idxs[tku] * D;
        #pragma unroll
        for (int i = 0; i < 8; ++i) {
            const int d = d0u + i * 4;
            const float4 qv = *(const float4*)&crow[d];
            float4 r = *(float4*)&res[tku][d];
            float e, qst, dd;
            e = qv.x - r.x; qst = r.x + e; dd = qst - r.x;
            lacc = fma((double)dd, (double)dd, lacc); qreg[i*4+0] += qst; r.x = r.x - qst;
            e = qv.y - r.y; qst = r.y + e; dd = qst - r.y;
            lacc = fma((double)dd, (double)dd, lacc); qreg[i*4+1] += qst; r.y = r.y - qst;
            e = qv.z - r.z; qst = r.z + e; dd = qst - r.z;
            lacc = fma((double)dd, (double)dd, lacc); qreg[i*4+2] += qst; r.z = r.z - qst;
            e = qv.w - r.w; qst = r.w + e; dd = qst - r.w;
            lacc = fma((double)dd, (double)dd, lacc); qreg[i*4+3] += qst; r.w = r.w - qst;
            *(float4*)&res[tku][d] = r;
        }
        __syncthreads();
    }

    #pragma unroll
    for (int i = 0; i < 8; ++i)
        *(float4*)&res[tku][d0u + i * 4] = *(float4*)&qreg[i * 4];
    __syncthreads();
    #pragma unroll
    for (int it = 0; it < 32; ++it) {
        const int d  = it * 8 + (tid >> 5);
        const int tk = tid & 31;
        out[(size_t)b * D * T + (size_t)d * T + t0 + tk] = res[tk][d];
    }

    fbv[tid] = lacc;
    __syncthreads();
    for (int s2 = 128; s2 >= 1; s2 >>= 1) {
        if (tid < s2) fbv[tid] += fbv[tid + s2];
        __syncthreads();
    }
    if (tid == 0) lpart[bid] = fbv[0];
}

// ---------------- finalize: loss mean + bandwidth scalar ----------------
__global__ __launch_bounds__(256) void finalize_kernel(
    const double* __restrict__ lpart, int nblk,
    const int* __restrict__ srp, float* __restrict__ out)
{
    __shared__ double sh[256];
    double a = 0.0;
    for (int i = threadIdx.x; i < nblk; i += 256) a += lpart[i];
    sh[threadIdx.x] = a;
    __syncthreads();
    for (int s = 128; s >= 1; s >>= 1) {
        if (threadIdx.x < s) sh[threadIdx.x] += sh[threadIdx.x + s];
        __syncthreads();
    }
    if (threadIdx.x == 0) {
        out[OFF_L]  = (float)(sh[0] / ((double)NQ * B * T * D));
        out[OFF_BW] = (float)((double)NQ * 10.0 * (double)srp[0] / 1000.0);
    }
}

extern "C" void kernel_launch(void* const* d_in, const int* in_sizes, int n_in,
                              void* d_out, int out_size, void* d_ws, size_t ws_size,
                              hipStream_t stream)
{
    const float* x  = (const float*)d_in[0];
    const float* cb = (const float*)d_in[1];
    const int*   sr = (const int*)d_in[2];
    float* out = (float*)d_out;

    // ws layout: cbn f64[8192] @0 (65536) | cbnf f32[8192] @65536 (32768)
    //            lpart f64[8192] @98304 (65536) | bfh @163840 (4 MiB) | bfl @4358144
    //            total 8552448 B
    double* cbn   = (double*)d_ws;
    float*  cbnf  = (float*)((char*)d_ws + 65536);
    double* lpart = (double*)((char*)d_ws + 98304);
    unsigned short* bfh = (unsigned short*)((char*)d_ws + 163840);
    unsigned short* bfl = (unsigned short*)((char*)d_ws + 4358144);

    hipLaunchKernelGGL(cbnorm_kernel, dim3(NQ * BINS / 4), dim3(256), 0, stream, cb, cbn, cbnf);

    if (ws_size >= (size_t)8552448) {
        hipLaunchKernelGGL(prep_bfrag, dim3(1024), dim3(256), 0, stream, cb, bfh, bfl);
        float* resb = out;   // quantized section doubles as residual buffer
        for (int q = 0; q < NQ; ++q) {
            hipLaunchKernelGGL(rvq_scan, dim3(B * (T / 64)), dim3(512), 0, stream,
                               (q == 0 ? x : (const float*)resb), resb, cb, cbn, cbnf,
                               bfh, bfl, out, lpart, q);
        }
        hipLaunchKernelGGL(final_sub, dim3((B * D * T) / 1024), dim3(256), 0, stream, x, resb);
        hipLaunchKernelGGL(finalize_kernel, dim3(1), dim3(256), 0, stream,
                           lpart, NQ * 1024, sr, out);
    } else {
        hipLaunchKernelGGL(rvq_main_old, dim3(B * (T / OTOK)), dim3(256), 0, stream,
                           x, cb, cbn, cbnf, out, lpart);
        hipLaunchKernelGGL(finalize_kernel, dim3(1), dim3(256), 0, stream,
                           lpart, B * (T / OTOK), sr, out);
    }
}

// Round 9
// 2204.685 us; speedup vs baseline: 2.8992x; 1.0102x over previous
//
#include <hip/hip_runtime.h>

#define B 16
#define D 256
#define T 4096
#define NQ 8
#define BINS 1024
#define EPS 0.008f

#define OFF_C  ((size_t)B * D * T)            // quantized elems = 16777216
#define OFF_BW (OFF_C + (size_t)NQ * B * T)   // + codes 524288 -> 17301504
#define OFF_L  (OFF_BW + 1)

typedef __attribute__((ext_vector_type(8))) short short8v;
typedef __attribute__((ext_vector_type(4))) float float4v;

// ---- LDS map (bytes) for rvq_scan (256 threads, 64 tokens, 4 blocks/CU) ----
#define BBUF   0        // 2 x 16384 double buffer (union RESF 16 tok x 257 x4 = 16448)
#define RESF   0
#define IDXS   32768    // i32[64]   -> 33024
#define FLAGS  33024    // i32[64]   -> 33280
#define G1L    33280    // f32[64]   -> 33536
#define RSTG   33536    // f32[256]  -> 34560
#define NORMS  34560    // f32[1024] -> 38656
#define REDW   38656    // f64[4]    -> 38688
#define REDIW  38688    // i32[4]    -> 38704
#define SMTOT  38704    // x4 = 154816 <= 163840 -> 4 blocks/CU

#define STAGE16(gp, loff) \
  __builtin_amdgcn_global_load_lds( \
      (const __attribute__((address_space(1))) unsigned int*)(gp), \
      (__attribute__((address_space(3))) unsigned int*)(smc + (loff)), 16, 0, 0)

__device__ __forceinline__ unsigned short f2bf(float f) {
    unsigned u = __float_as_uint(f);
    unsigned r = (u + 0x7fffu + ((u >> 16) & 1u)) >> 16;   // RNE
    return (unsigned short)r;
}
__device__ __forceinline__ float bf2f(unsigned short h) {
    return __uint_as_float(((unsigned)h) << 16);
}

// ---------------- codebook norms: f64 (exact fallback) + f32 (scan) ----------------
__global__ __launch_bounds__(256) void cbnorm_kernel(const float* __restrict__ cb,
                                                     double* __restrict__ cbn,
                                                     float* __restrict__ cbnf)
{
    const int wave = threadIdx.x >> 6;
    const int lane = threadIdx.x & 63;
    const int bin = blockIdx.x * 4 + wave;          // 0..8191 (q*1024+k)
    const float4 v = *(const float4*)&cb[(size_t)bin * D + lane * 4];
    double a = (double)v.x * v.x + (double)v.y * v.y
             + (double)v.z * v.z + (double)v.w * v.w;
    #pragma unroll
    for (int off = 32; off >= 1; off >>= 1)
        a += __shfl_xor(a, off, 64);
    if (lane == 0) { cbn[bin] = a; cbnf[bin] = (float)a; }
}

// ---------------- prep: codebook -> bf16 hi/lo planes in MFMA-B-fragment order ----
// frag c = q*512 + ntg*8 + ks ; lane l, j -> B[k=ks*32+(l>>4)*8+j][n=ntg*16+(l&15)]
__global__ __launch_bounds__(256) void prep_bfrag(const float* __restrict__ cb,
                                                  unsigned short* __restrict__ bfh,
                                                  unsigned short* __restrict__ bfl)
{
    const int c = blockIdx.x * 4 + (threadIdx.x >> 6);   // 0..4095
    const int lane = threadIdx.x & 63;
    const int q = c >> 9, ntg = (c >> 3) & 63, ks = c & 7;
    const float* src = cb + ((size_t)q * BINS + ntg * 16 + (lane & 15)) * D
                         + ks * 32 + (lane >> 4) * 8;
    short8v h, l;
    #pragma unroll
    for (int j = 0; j < 8; ++j) {
        const float v = src[j];
        const unsigned short hh = f2bf(v);
        h[j] = (short)hh;
        l[j] = (short)f2bf(v - bf2f(hh));
    }
    const size_t off = ((size_t)c * 64 + lane) * 8;
    *(short8v*)(bfh + off) = h;
    *(short8v*)(bfl + off) = l;
}

// ---------------- per-stage scan+update (one launch per q) ----------------
// 256 threads, 64 tokens/block, 4 waves; wave w owns tokens w*16..w*16+15 and
// scans ALL 1024 bins in 64 steps of 16 bins. A hi/lo in regs (64), B via LDS
// double buffer + counted vmcnt. 4 independent blocks per CU.
__global__ __launch_bounds__(256, 4) void rvq_scan(
    const float* __restrict__ rsrc, float* __restrict__ rdst,
    const float* __restrict__ cb,
    const double* __restrict__ cbn, const float* __restrict__ cbnf,
    const unsigned short* __restrict__ bfh, const unsigned short* __restrict__ bfl,
    float* __restrict__ out, double* __restrict__ lpart, int q)
{
    __shared__ __align__(16) char smem[SMTOT];
    char*   smc    = smem;
    float*  resf   = (float*)(smem + RESF);
    int*    idxsL  = (int*)(smem + IDXS);
    int*    flagsL = (int*)(smem + FLAGS);
    float*  g1L    = (float*)(smem + G1L);
    float*  rstage = (float*)(smem + RSTG);
    float*  normsp = (float*)(smem + NORMS);
    double* redw   = (double*)(smem + REDW);
    int*    rediw  = (int*)(smem + REDIW);

    const int tid  = threadIdx.x;
    const int bid  = blockIdx.x;
    const int b    = bid >> 6;            // T/64 = 64 tiles per batch
    const int t0   = (bid & 63) * 64;
    const int w    = tid >> 6;            // 0..3
    const int lane = tid & 63;
    const int col  = lane & 15;
    const int rgrp = lane >> 4;
    const int rot  = (bid * 5) & 63;      // per-block bin-group rotation (L2 spread)

    const float* rs = rsrc + (size_t)b * D * T + t0;
    float*       rd = rdst + (size_t)b * D * T + t0;

    // ---- 1. residual -> A-fragments, 4 chunks of 16 tokens through small LDS
    short8v Ah[8], Al[8];
    #pragma unroll 1
    for (int ch = 0; ch < 4; ++ch) {
        #pragma unroll 1
        for (int it = 0; it < 16; ++it) {
            const int lin = it * 256 + tid;
            const int tk = lin & 15, d = lin >> 4;
            resf[tk * 257 + d] =
                __builtin_nontemporal_load(&rs[(size_t)d * T + ch * 16 + tk]);
        }
        __syncthreads();
        if (w == ch) {
            #pragma unroll
            for (int ks = 0; ks < 8; ++ks) {
                short8v h, l;
                #pragma unroll
                for (int j = 0; j < 8; ++j) {
                    const float v = resf[col * 257 + ks * 32 + rgrp * 8 + j];
                    const unsigned short hh = f2bf(v);
                    h[j] = (short)hh;
                    l[j] = (short)f2bf(v - bf2f(hh));
                }
                Ah[ks] = h; Al[ks] = l;
            }
        }
        __syncthreads();
    }
    for (int i = tid; i < BINS; i += 256) normsp[i] = cbnf[q * BINS + i];
    __syncthreads();   // norms visible; resf dead -> BBUF owns the union

    // ---- 2. staging: wave (plane = w>>1, part = w&1) stages 4 KB per step
    const int plane = w >> 1, part = w & 1;
    const unsigned short* sbase = plane ? bfl : bfh;

    #pragma unroll
    for (int pnt = 0; pnt < 2; ++pnt) {
        const int ntg = (pnt + rot) & 63;
        const unsigned short* srcp =
            sbase + ((size_t)q * 512 + ntg * 8 + part * 4) * 512 + lane * 8;
        const int dstb = pnt * 16384 + plane * 8192 + part * 4096;
        #pragma unroll
        for (int i = 0; i < 4; ++i) STAGE16(srcp + i * 512, dstb + i * 1024);
    }

    // ---- 3. scan loop: 64 steps x 16 bins, counted-vmcnt double buffer
    float bv1[4], bv2[4]; int bi1[4];
    #pragma unroll
    for (int s = 0; s < 4; ++s) { bv1[s] = 3.4e38f; bv2[s] = 3.4e38f; bi1[s] = 0; }

    #pragma unroll 1
    for (int nt = 0; nt < 64; ++nt) {
        if (nt == 63) { asm volatile("s_waitcnt vmcnt(0)" ::: "memory"); }
        else          { asm volatile("s_waitcnt vmcnt(4)" ::: "memory"); }
        __builtin_amdgcn_s_barrier();
        asm volatile("" ::: "memory");

        const int ntr = (nt + rot) & 63;
        const int cur = nt & 1;
        const char* bb = smc + cur * 16384;
        const float qn = normsp[ntr * 16 + col];

        float4v a0 = {0,0,0,0}, a1 = {0,0,0,0}, a2 = {0,0,0,0}, a3 = {0,0,0,0};
        #pragma unroll
        for (int ks = 0; ks < 8; ++ks) {
            const short8v Bh = *(const short8v*)(bb + ks * 1024 + lane * 16);
            const short8v Bl = *(const short8v*)(bb + 8192 + ks * 1024 + lane * 16);
            float4v& c = (ks & 3) == 0 ? a0 : ((ks & 3) == 1 ? a1 : ((ks & 3) == 2 ? a2 : a3));
            c = __builtin_amdgcn_mfma_f32_16x16x32_bf16(Al[ks], Bh, c, 0, 0, 0);
            c = __builtin_amdgcn_mfma_f32_16x16x32_bf16(Ah[ks], Bl, c, 0, 0, 0);
            c = __builtin_amdgcn_mfma_f32_16x16x32_bf16(Ah[ks], Bh, c, 0, 0, 0);
        }

        const int binb = ntr * 16 + col;
        #pragma unroll
        for (int r = 0; r < 4; ++r) {
            const float s0 = fmaf(-2.0f, (a0[r] + a1[r]) + (a2[r] + a3[r]), qn);
            if (s0 < bv1[r]) { bv2[r] = bv1[r]; bv1[r] = s0; bi1[r] = binb; }
            else if (s0 < bv2[r]) bv2[r] = s0;
        }

        __builtin_amdgcn_s_barrier();
        asm volatile("" ::: "memory");
        if (nt <= 61) {
            const int ntg = (nt + 2 + rot) & 63;
            const unsigned short* srcp =
                sbase + ((size_t)q * 512 + ntg * 8 + part * 4) * 512 + lane * 8;
            const int dstb = cur * 16384 + plane * 8192 + part * 4096;
            #pragma unroll
            for (int i = 0; i < 4; ++i) STAGE16(srcp + i * 512, dstb + i * 1024);
        }
    }

    // ---- 4. top-2 merge across 16 cols (within wave), index tiebreak; write direct
    #pragma unroll
    for (int off = 1; off <= 8; off <<= 1) {
        #pragma unroll
        for (int sl = 0; sl < 4; ++sl) {
            const float ov1 = __shfl_xor(bv1[sl], off, 64);
            const float ov2 = __shfl_xor(bv2[sl], off, 64);
            const int   oi  = __shfl_xor(bi1[sl], off, 64);
            if (ov1 < bv1[sl] || (ov1 == bv1[sl] && oi < bi1[sl])) {
                bv2[sl] = fminf(bv1[sl], ov2); bv1[sl] = ov1; bi1[sl] = oi;
            } else {
                bv2[sl] = fminf(bv2[sl], ov1);
            }
        }
    }
    if (col == 0) {
        #pragma unroll
        for (int r = 0; r < 4; ++r) {
            const int tk = w * 16 + rgrp * 4 + r;
            idxsL[tk]  = bi1[r];
            g1L[tk]    = bv1[r];
            flagsL[tk] = (bv2[r] - bv1[r] < EPS) ? 1 : 0;
        }
    }
    __syncthreads();

    // ---- 5. exact fallback for near-tie tokens: f32 prefilter + f64 for bins
    //         within g1 + 0.0065 (covers scan err ~2e-3 + rescan err ~1e-3)
    const float* cbq = cb + (size_t)q * BINS * D;
    #pragma unroll 1
    for (int tk2 = 0; tk2 < 64; ++tk2) {
        if (!flagsL[tk2]) continue;                  // uniform branch (LDS)
        rstage[tid] = rs[(size_t)tid * T + tk2];     // tid == d, D == 256
        __syncthreads();
        const float thr = g1L[tk2] + 0.0065f;
        double bb2 = 1e300; int bbi = 0x7fffffff;
        #pragma unroll 1
        for (int jj = 0; jj < 4; ++jj) {
            const int bin = tid + 256 * jj;          // ascending -> lowest-idx kept
            const float* crow = cbq + (size_t)bin * D;
            float f0 = 0.f, f1 = 0.f, f2 = 0.f, f3 = 0.f;
            for (int d = 0; d < D; d += 4) {
                const float4 rv = *(const float4*)&rstage[d];
                const float4 cv = *(const float4*)&crow[d];
                f0 = fmaf(rv.x, cv.x, f0); f1 = fmaf(rv.y, cv.y, f1);
                f2 = fmaf(rv.z, cv.z, f2); f3 = fmaf(rv.w, cv.w, f3);
            }
            const float sf = fmaf(-2.0f, (f0 + f1) + (f2 + f3), normsp[bin]);
            if (sf <= thr) {                         // rare: ~1-3 bins per token
                double a = 0.0;
                for (int d = 0; d < D; d += 4) {
                    const float4 rv = *(const float4*)&rstage[d];
                    const float4 cv = *(const float4*)&crow[d];
                    a = fma((double)rv.x, (double)cv.x, a);
                    a = fma((double)rv.y, (double)cv.y, a);
                    a = fma((double)rv.z, (double)cv.z, a);
                    a = fma((double)rv.w, (double)cv.w, a);
                }
                const double s = fma(-2.0, a, cbn[q * BINS + bin]);
                if (s < bb2) { bb2 = s; bbi = bin; }
            }
        }
        #pragma unroll
        for (int off = 32; off >= 1; off >>= 1) {
            const double ov = __shfl_xor(bb2, off, 64);
            const int   oi  = __shfl_xor(bbi, off, 64);
            if (ov < bb2 || (ov == bb2 && oi < bbi)) { bb2 = ov; bbi = oi; }
        }
        if (lane == 0) { redw[w] = bb2; rediw[w] = bbi; }
        __syncthreads();
        if (tid == 0) {
            double mv = redw[0]; int mi = rediw[0];
            #pragma unroll
            for (int wv = 1; wv < 4; ++wv) {
                const double ov = redw[wv]; const int oi = rediw[wv];
                if (ov < mv || (ov == mv && oi < mi)) { mv = ov; mi = oi; }
            }
            idxsL[tk2] = mi;
        }
        __syncthreads();
    }

    // ---- 6. codes
    if (tid < 64)
        out[OFF_C + (size_t)q * B * T + (size_t)b * T + t0 + tid] = (float)idxsL[tid];

    // ---- 7. faithful f32 straight-through update (coalesced) + loss
    double lacc = 0.0;
    #pragma unroll 1
    for (int it = 0; it < 64; ++it) {
        const int lin = it * 256 + tid;
        const int tk = lin & 63, d = lin >> 6;
        const float r  = __builtin_nontemporal_load(&rs[(size_t)d * T + tk]);
        const float cv = cbq[(size_t)idxsL[tk] * D + d];
        const float e   = cv - r;
        const float qst = r + e;
        const float dd  = qst - r;
        lacc = fma((double)dd, (double)dd, lacc);
        __builtin_nontemporal_store(r - qst, &rd[(size_t)d * T + tk]);
    }

    // ---- 8. deterministic per-block loss partial (wave shuffle + tiny LDS)
    #pragma unroll
    for (int off = 32; off >= 1; off >>= 1)
        lacc += __shfl_xor(lacc, off, 64);
    if (lane == 0) redw[w] = lacc;
    __syncthreads();
    if (tid == 0)
        lpart[(size_t)q * 1024 + bid] = (redw[0] + redw[1]) + (redw[2] + redw[3]);
}

// ---------------- final: quantized = x - res, in place on out[0:B*D*T) ----------
__global__ __launch_bounds__(256) void final_sub(const float* __restrict__ x,
                                                 float* __restrict__ o)
{
    const size_t i = ((size_t)blockIdx.x * 256 + threadIdx.x) * 4;
    const float4v xv = __builtin_nontemporal_load((const float4v*)(x + i));
    const float4v ov = __builtin_nontemporal_load((const float4v*)(o + i));
    const float4v r = xv - ov;
    __builtin_nontemporal_store(r, (float4v*)(o + i));
}

// ---------------- OLD PATH (R2, known-good) kept as ws-size fallback ----------------
#define OTOK 32
#define ORS 260
__global__ __launch_bounds__(256, 3) void rvq_main_old(
    const float* __restrict__ x, const float* __restrict__ cb,
    const double* __restrict__ cbn, const float* __restrict__ cbnf,
    float* __restrict__ out, double* __restrict__ lpart)
{
    __shared__ float  res[OTOK][ORS];
    __shared__ float  bv1s[OTOK][16];
    __shared__ float  bv2s[OTOK][16];
    __shared__ int    bi1s[OTOK][16];
    __shared__ int    idxs[OTOK];
    __shared__ int    flags[OTOK];
    __shared__ double fbv[256];
    __shared__ int    fbi[256];

    const int tid = threadIdx.x;
    const int bid = blockIdx.x;
    const int b  = bid >> 7;
    const int t0 = (bid & 127) * OTOK;

    const float* xb = x + (size_t)b * D * T + t0;
    #pragma unroll
    for (int it = 0; it < 32; ++it) {
        const int d  = it * 8 + (tid >> 5);
        const int tk = tid & 31;
        res[tk][d] = xb[(size_t)d * T + tk];
    }
    __syncthreads();

    float qreg[32];
    #pragma unroll
    for (int i = 0; i < 32; ++i) qreg[i] = 0.0f;

    const int tg = tid & 15;
    const int bg = tid >> 4;
    const int tku = tid >> 3;
    const int d0u = (tid & 7) * 32;
    double lacc = 0.0;

    for (int q = 0; q < NQ; ++q) {
        const float*  cbq = cb   + (size_t)q * BINS * D;
        const float*  cnf = cbnf + (size_t)q * BINS;
        const double* cnd = cbn  + (size_t)q * BINS;

        float bvA = 3.4e38f, bvA2 = 3.4e38f;  int biA = 0;
        float bvB = 3.4e38f, bvB2 = 3.4e38f;  int biB = 0;

        for (int iter = 0; iter < 8; ++iter) {
            const int binbase = iter * 128 + bg * 8;
            float a0[8], a1[8];
            #pragma unroll
            for (int j = 0; j < 8; ++j) { a0[j] = 0.0f; a1[j] = 0.0f; }
            for (int d = 0; d < D; d += 4) {
                const float4 r0 = *(const float4*)&res[tg][d];
                const float4 r1 = *(const float4*)&res[tg + 16][d];
                #pragma unroll
                for (int j = 0; j < 8; ++j) {
                    const float4 c = *(const float4*)&cbq[(size_t)(binbase + j) * D + d];
                    a0[j] = fmaf(r0.x, c.x, a0[j]); a0[j] = fmaf(r0.y, c.y, a0[j]);
                    a0[j] = fmaf(r0.z, c.z, a0[j]); a0[j] = fmaf(r0.w, c.w, a0[j]);
                    a1[j] = fmaf(r1.x, c.x, a1[j]); a1[j] = fmaf(r1.y, c.y, a1[j]);
                    a1[j] = fmaf(r1.z, c.z, a1[j]); a1[j] = fmaf(r1.w, c.w, a1[j]);
                }
            }
            #pragma unroll
            for (int j = 0; j < 8; ++j) {
                const int bin = binbase + j;
                const float qn = cnf[bin];
                const float s0 = fmaf(-2.0f, a0[j], qn);
                const float s1 = fmaf(-2.0f, a1[j], qn);
                if (s0 < bvA) { bvA2 = bvA; bvA = s0; biA = bin; }
                else if (s0 < bvA2) { bvA2 = s0; }
                if (s1 < bvB) { bvB2 = bvB; bvB = s1; biB = bin; }
                else if (s1 < bvB2) { bvB2 = s1; }
            }
        }
        bv1s[tg][bg]      = bvA;  bv2s[tg][bg]      = bvA2;  bi1s[tg][bg]      = biA;
        bv1s[tg + 16][bg] = bvB;  bv2s[tg + 16][bg] = bvB2;  bi1s[tg + 16][bg] = biB;
        __syncthreads();

        if (tid < OTOK) {
            float g1 = bv1s[tid][0], g2 = bv2s[tid][0];
            int   gi = bi1s[tid][0];
            #pragma unroll
            for (int g = 1; g < 16; ++g) {
                const float v1 = bv1s[tid][g];
                const float v2 = bv2s[tid][g];
                const int   i1 = bi1s[tid][g];
                if (v1 < g1 || (v1 == g1 && i1 < gi)) { g2 = fminf(g1, v2); g1 = v1; gi = i1; }
                else g2 = fminf(g2, v1);
            }
            idxs[tid]  = gi;
            flags[tid] = (g2 - g1 < 0.02f) ? 1 : 0;
        }
        __syncthreads();

        for (int tok = 0; tok < OTOK; ++tok) {
            if (!flags[tok]) continue;
            double bb = 1e300; int bbi = 0;
            #pragma unroll
            for (int jj = 0; jj < 4; ++jj) {
                const int bin = tid + 256 * jj;
                const float* crow = cbq + (size_t)bin * D;
                double a = 0.0;
                for (int d = 0; d < D; d += 4) {
                    const float4 r = *(const float4*)&res[tok][d];
                    const float4 c = *(const float4*)&crow[d];
                    a = fma((double)r.x, (double)c.x, a);
                    a = fma((double)r.y, (double)c.y, a);
                    a = fma((double)r.z, (double)c.z, a);
                    a = fma((double)r.w, (double)c.w, a);
                }
                const double s = fma(-2.0, a, cnd[bin]);
                if (s < bb) { bb = s; bbi = bin; }
            }
            fbv[tid] = bb; fbi[tid] = bbi;
            __syncthreads();
            for (int s2 = 128; s2 >= 1; s2 >>= 1) {
                if (tid < s2) {
                    const double ov = fbv[tid + s2]; const int oi = fbi[tid + s2];
                    const double mv = fbv[tid];      const int mi = fbi[tid];
                    if (ov < mv || (ov == mv && oi < mi)) { fbv[tid] = ov; fbi[tid] = oi; }
                }
                __syncthreads();
            }
            if (tid == 0) idxs[tok] = fbi[0];
            __syncthreads();
        }

        if (tid < OTOK)
            out[OFF_C + (size_t)q * B * T + (size_t)b * T + t0 + tid] = (float)idxs[tid];

        const float* crow = cbq + (size_t)idxs[tku] * D;
        #pragma unroll
        for (int i = 0; i < 8; ++i) {
            const int d = d0u + i * 4;
            const float4 qv = *(const float4*)&crow[d];
            float4 r = *(float4*)&res[tku][d];
            float e, qst, dd;
            e = qv.x - r.x; qst = r.x + e; dd = qst - r.x;
            lacc = fma((double)dd, (double)dd, lacc); qreg[i*4+0] += qst; r.x = r.x - qst;
            e = qv.y - r.y; qst = r.y + e; dd = qst - r.y;
            lacc = fma((double)dd, (double)dd, lacc); qreg[i*4+1] += qst; r.y = r.y - qst;
            e = qv.z - r.z; qst = r.z + e; dd = qst - r.z;
            lacc = fma((double)dd, (double)dd, lacc); qreg[i*4+2] += qst; r.z = r.z - qst;
            e = qv.w - r.w; qst = r.w + e; dd = qst - r.w;
            lacc = fma((double)dd, (double)dd, lacc); qreg[i*4+3] += qst; r.w = r.w - qst;
            *(float4*)&res[tku][d] = r;
        }
        __syncthreads();
    }

    #pragma unroll
    for (int i = 0; i < 8; ++i)
        *(float4*)&res[tku][d0u + i * 4] = *(float4*)&qreg[i * 4];
    __syncthreads();
    #pragma unroll
    for (int it = 0; it < 32; ++it) {
        const int d  = it * 8 + (tid >> 5);
        const int tk = tid & 31;
        out[(size_t)b * D * T + (size_t)d * T + t0 + tk] = res[tk][d];
    }

    fbv[tid] = lacc;
    __syncthreads();
    for (int s2 = 128; s2 >= 1; s2 >>= 1) {
        if (tid < s2) fbv[tid] += fbv[tid + s2];
        __syncthreads();
    }
    if (tid == 0) lpart[bid] = fbv[0];
}

// ---------------- finalize: loss mean + bandwidth scalar ----------------
__global__ __launch_bounds__(256) void finalize_kernel(
    const double* __restrict__ lpart, int nblk,
    const int* __restrict__ srp, float* __restrict__ out)
{
    __shared__ double sh[256];
    double a = 0.0;
    for (int i = threadIdx.x; i < nblk; i += 256) a += lpart[i];
    sh[threadIdx.x] = a;
    __syncthreads();
    for (int s = 128; s >= 1; s >>= 1) {
        if (threadIdx.x < s) sh[threadIdx.x] += sh[threadIdx.x + s];
        __syncthreads();
    }
    if (threadIdx.x == 0) {
        out[OFF_L]  = (float)(sh[0] / ((double)NQ * B * T * D));
        out[OFF_BW] = (float)((double)NQ * 10.0 * (double)srp[0] / 1000.0);
    }
}

extern "C" void kernel_launch(void* const* d_in, const int* in_sizes, int n_in,
                              void* d_out, int out_size, void* d_ws, size_t ws_size,
                              hipStream_t stream)
{
    const float* x  = (const float*)d_in[0];
    const float* cb = (const float*)d_in[1];
    const int*   sr = (const int*)d_in[2];
    float* out = (float*)d_out;

    // ws layout: cbn f64[8192] @0 (65536) | cbnf f32[8192] @65536 (32768)
    //            lpart f64[8192] @98304 (65536) | bfh @163840 (4 MiB) | bfl @4358144
    //            total 8552448 B
    double* cbn   = (double*)d_ws;
    float*  cbnf  = (float*)((char*)d_ws + 65536);
    double* lpart = (double*)((char*)d_ws + 98304);
    unsigned short* bfh = (unsigned short*)((char*)d_ws + 163840);
    unsigned short* bfl = (unsigned short*)((char*)d_ws + 4358144);

    hipLaunchKernelGGL(cbnorm_kernel, dim3(NQ * BINS / 4), dim3(256), 0, stream, cb, cbn, cbnf);

    if (ws_size >= (size_t)8552448) {
        hipLaunchKernelGGL(prep_bfrag, dim3(1024), dim3(256), 0, stream, cb, bfh, bfl);
        float* resb = out;   // quantized section doubles as residual buffer
        for (int q = 0; q < NQ; ++q) {
            hipLaunchKernelGGL(rvq_scan, dim3(B * (T / 64)), dim3(256), 0, stream,
                               (q == 0 ? x : (const float*)resb), resb, cb, cbn, cbnf,
                               bfh, bfl, out, lpart, q);
        }
        hipLaunchKernelGGL(final_sub, dim3((B * D * T) / 1024), dim3(256), 0, stream, x, resb);
        hipLaunchKernelGGL(finalize_kernel, dim3(1), dim3(256), 0, stream,
                           lpart, NQ * 1024, sr, out);
    } else {
        hipLaunchKernelGGL(rvq_main_old, dim3(B * (T / OTOK)), dim3(256), 0, stream,
                           x, cb, cbn, cbnf, out, lpart);
        hipLaunchKernelGGL(finalize_kernel, dim3(1), dim3(256), 0, stream,
                           lpart, B * (T / OTOK), sr, out);
    }
}

// Round 10
// 1652.359 us; speedup vs baseline: 3.8683x; 1.3343x over previous
//
#include <hip/hip_runtime.h>

#define B 16
#define D 256
#define T 4096
#define NQ 8
#define BINS 1024
#define EPS 0.008f

#define OFF_C  ((size_t)B * D * T)            // quantized elems = 16777216
#define OFF_BW (OFF_C + (size_t)NQ * B * T)   // + codes 524288 -> 17301504
#define OFF_L  (OFF_BW + 1)

typedef __attribute__((ext_vector_type(8))) short short8v;
typedef __attribute__((ext_vector_type(4))) float float4v;

// ---- LDS map (bytes) for rvq_scan (256 threads, 64 tokens, 4 blocks/CU) ----
#define BBUF   0        // 2 x 16384 double buffer (union RESF/ROWS 16x257x4 = 16448)
#define RESF   0
#define IDXS   32768    // i32[64]   -> 33024
#define FLAGS  33024    // i32[64]   -> 33280
#define G1L    33280    // f32[64]   -> 33536
#define RSTG   33536    // f32[256]  -> 34560
#define NORMS  34560    // f32[1024] -> 38656
#define REDW   38656    // f64[4]    -> 38688
#define REDIW  38688    // i32[4]    -> 38704
#define SMTOT  38704    // x4 = 154816 <= 163840 -> 4 blocks/CU

#define STAGE16(gp, loff) \
  __builtin_amdgcn_global_load_lds( \
      (const __attribute__((address_space(1))) unsigned int*)(gp), \
      (__attribute__((address_space(3))) unsigned int*)(smc + (loff)), 16, 0, 0)

__device__ __forceinline__ unsigned short f2bf(float f) {
    unsigned u = __float_as_uint(f);
    unsigned r = (u + 0x7fffu + ((u >> 16) & 1u)) >> 16;   // RNE
    return (unsigned short)r;
}
__device__ __forceinline__ float bf2f(unsigned short h) {
    return __uint_as_float(((unsigned)h) << 16);
}

// ---------------- codebook norms: f64 (exact fallback) + f32 (scan) ----------------
__global__ __launch_bounds__(256) void cbnorm_kernel(const float* __restrict__ cb,
                                                     double* __restrict__ cbn,
                                                     float* __restrict__ cbnf)
{
    const int wave = threadIdx.x >> 6;
    const int lane = threadIdx.x & 63;
    const int bin = blockIdx.x * 4 + wave;          // 0..8191 (q*1024+k)
    const float4 v = *(const float4*)&cb[(size_t)bin * D + lane * 4];
    double a = (double)v.x * v.x + (double)v.y * v.y
             + (double)v.z * v.z + (double)v.w * v.w;
    #pragma unroll
    for (int off = 32; off >= 1; off >>= 1)
        a += __shfl_xor(a, off, 64);
    if (lane == 0) { cbn[bin] = a; cbnf[bin] = (float)a; }
}

// ---------------- prep: codebook -> bf16 hi/lo planes in MFMA-B-fragment order ----
// frag c = q*512 + ntg*8 + ks ; lane l, j -> B[k=ks*32+(l>>4)*8+j][n=ntg*16+(l&15)]
__global__ __launch_bounds__(256) void prep_bfrag(const float* __restrict__ cb,
                                                  unsigned short* __restrict__ bfh,
                                                  unsigned short* __restrict__ bfl)
{
    const int c = blockIdx.x * 4 + (threadIdx.x >> 6);   // 0..4095
    const int lane = threadIdx.x & 63;
    const int q = c >> 9, ntg = (c >> 3) & 63, ks = c & 7;
    const float* src = cb + ((size_t)q * BINS + ntg * 16 + (lane & 15)) * D
                         + ks * 32 + (lane >> 4) * 8;
    short8v h, l;
    #pragma unroll
    for (int j = 0; j < 8; ++j) {
        const float v = src[j];
        const unsigned short hh = f2bf(v);
        h[j] = (short)hh;
        l[j] = (short)f2bf(v - bf2f(hh));
    }
    const size_t off = ((size_t)c * 64 + lane) * 8;
    *(short8v*)(bfh + off) = h;
    *(short8v*)(bfl + off) = l;
}

// ---------------- per-stage scan+update (one launch per q) ----------------
// 256 threads, 64 tokens/block, 4 waves; wave w owns tokens w*16..w*16+15 and
// scans ALL 1024 bins in 64 steps of 16 bins. A hi/lo in regs; B via LDS
// double buffer, ONE barrier per step (issue-at-top), setprio around MFMA.
__global__ __launch_bounds__(256, 4) void rvq_scan(
    const float* __restrict__ rsrc, float* __restrict__ rdst,
    const float* __restrict__ cb,
    const double* __restrict__ cbn, const float* __restrict__ cbnf,
    const unsigned short* __restrict__ bfh, const unsigned short* __restrict__ bfl,
    float* __restrict__ out, double* __restrict__ lpart, int q)
{
    __shared__ __align__(16) char smem[SMTOT];
    char*   smc    = smem;
    float*  resf   = (float*)(smem + RESF);   // also: rows[16][257] in update phase
    int*    idxsL  = (int*)(smem + IDXS);
    int*    flagsL = (int*)(smem + FLAGS);
    float*  g1L    = (float*)(smem + G1L);
    float*  rstage = (float*)(smem + RSTG);
    float*  normsp = (float*)(smem + NORMS);
    double* redw   = (double*)(smem + REDW);
    int*    rediw  = (int*)(smem + REDIW);

    const int tid  = threadIdx.x;
    const int bid  = blockIdx.x;
    const int b    = bid >> 6;            // T/64 = 64 tiles per batch
    const int t0   = (bid & 63) * 64;
    const int w    = tid >> 6;            // 0..3
    const int lane = tid & 63;
    const int col  = lane & 15;
    const int rgrp = lane >> 4;
    const int rot  = (bid * 5) & 63;      // per-block bin-group rotation (L2 spread)

    const float* rs = rsrc + (size_t)b * D * T + t0;
    float*       rd = rdst + (size_t)b * D * T + t0;

    // ---- 0. norms (doesn't alias resf)
    for (int i = tid; i < BINS; i += 256) normsp[i] = cbnf[q * BINS + i];

    // ---- 1. residual -> A-fragments, 4 chunks of 16 tokens through small LDS
    short8v Ah[8], Al[8];
    #pragma unroll 1
    for (int ch = 0; ch < 4; ++ch) {
        #pragma unroll 1
        for (int it = 0; it < 16; ++it) {
            const int lin = it * 256 + tid;
            const int tk = lin & 15, d = lin >> 4;
            resf[tk * 257 + d] = rs[(size_t)d * T + ch * 16 + tk];
        }
        __syncthreads();
        if (w == ch) {
            #pragma unroll
            for (int ks = 0; ks < 8; ++ks) {
                short8v h, l;
                #pragma unroll
                for (int j = 0; j < 8; ++j) {
                    const float v = resf[col * 257 + ks * 32 + rgrp * 8 + j];
                    const unsigned short hh = f2bf(v);
                    h[j] = (short)hh;
                    l[j] = (short)f2bf(v - bf2f(hh));
                }
                Ah[ks] = h; Al[ks] = l;
            }
        }
        __syncthreads();
    }
    // resf dead; BBUF owns the union from here

    // ---- 2. staging setup: wave (plane = w>>1, part = w&1) stages 4 KB per step
    const int plane = w >> 1, part = w & 1;
    const unsigned short* sbase = plane ? bfl : bfh;

    // prologue: issue buf0 loads (bin-group rot)
    {
        const unsigned short* srcp =
            sbase + ((size_t)q * 512 + rot * 8 + part * 4) * 512 + lane * 8;
        const int dstb = plane * 8192 + part * 4096;
        #pragma unroll
        for (int i = 0; i < 4; ++i) STAGE16(srcp + i * 512, dstb + i * 1024);
    }

    // ---- 3. scan loop: 64 steps x 16 bins, ONE barrier per step
    float bv1[4], bv2[4]; int bi1[4];
    #pragma unroll
    for (int s = 0; s < 4; ++s) { bv1[s] = 3.4e38f; bv2[s] = 3.4e38f; bi1[s] = 0; }

    #pragma unroll 1
    for (int nt = 0; nt < 64; ++nt) {
        // only my 4 loads (for buf cur) are outstanding -> exact wait
        asm volatile("s_waitcnt vmcnt(0)" ::: "memory");
        __builtin_amdgcn_s_barrier();     // everyone's loads done AND everyone
        asm volatile("" ::: "memory");    // finished reading buf cur^1 last step

        const int cur = nt & 1;
        // issue next step's loads into buf cur^1 (overlaps with compute below)
        if (nt < 63) {
            const int ntg = (nt + 1 + rot) & 63;
            const unsigned short* srcp =
                sbase + ((size_t)q * 512 + ntg * 8 + part * 4) * 512 + lane * 8;
            const int dstb = (cur ^ 1) * 16384 + plane * 8192 + part * 4096;
            #pragma unroll
            for (int i = 0; i < 4; ++i) STAGE16(srcp + i * 512, dstb + i * 1024);
        }
        asm volatile("" ::: "memory");

        const int ntr = (nt + rot) & 63;
        const char* bb = smc + cur * 16384;
        const float qn = normsp[ntr * 16 + col];

        float4v a0 = {0,0,0,0}, a1 = {0,0,0,0}, a2 = {0,0,0,0}, a3 = {0,0,0,0};
        __builtin_amdgcn_s_setprio(1);
        #pragma unroll
        for (int ks = 0; ks < 8; ++ks) {
            const short8v Bh = *(const short8v*)(bb + ks * 1024 + lane * 16);
            const short8v Bl = *(const short8v*)(bb + 8192 + ks * 1024 + lane * 16);
            float4v& c = (ks & 3) == 0 ? a0 : ((ks & 3) == 1 ? a1 : ((ks & 3) == 2 ? a2 : a3));
            c = __builtin_amdgcn_mfma_f32_16x16x32_bf16(Al[ks], Bh, c, 0, 0, 0);
            c = __builtin_amdgcn_mfma_f32_16x16x32_bf16(Ah[ks], Bl, c, 0, 0, 0);
            c = __builtin_amdgcn_mfma_f32_16x16x32_bf16(Ah[ks], Bh, c, 0, 0, 0);
        }
        __builtin_amdgcn_s_setprio(0);

        const int binb = ntr * 16 + col;
        #pragma unroll
        for (int r = 0; r < 4; ++r) {
            const float s0 = fmaf(-2.0f, (a0[r] + a1[r]) + (a2[r] + a3[r]), qn);
            if (s0 < bv1[r]) { bv2[r] = bv1[r]; bv1[r] = s0; bi1[r] = binb; }
            else if (s0 < bv2[r]) bv2[r] = s0;
        }
    }

    // ---- 4. top-2 merge across 16 cols (within wave), index tiebreak
    #pragma unroll
    for (int off = 1; off <= 8; off <<= 1) {
        #pragma unroll
        for (int sl = 0; sl < 4; ++sl) {
            const float ov1 = __shfl_xor(bv1[sl], off, 64);
            const float ov2 = __shfl_xor(bv2[sl], off, 64);
            const int   oi  = __shfl_xor(bi1[sl], off, 64);
            if (ov1 < bv1[sl] || (ov1 == bv1[sl] && oi < bi1[sl])) {
                bv2[sl] = fminf(bv1[sl], ov2); bv1[sl] = ov1; bi1[sl] = oi;
            } else {
                bv2[sl] = fminf(bv2[sl], ov1);
            }
        }
    }
    if (col == 0) {
        #pragma unroll
        for (int r = 0; r < 4; ++r) {
            const int tk = w * 16 + rgrp * 4 + r;
            idxsL[tk]  = bi1[r];
            g1L[tk]    = bv1[r];
            flagsL[tk] = (bv2[r] - bv1[r] < EPS) ? 1 : 0;
        }
    }
    __syncthreads();

    // ---- 5. exact fallback for near-tie tokens: f32 prefilter + f64 for bins
    //         within g1 + 0.0065 (covers scan err ~2e-3 + rescan err ~1e-3)
    const float* cbq = cb + (size_t)q * BINS * D;
    #pragma unroll 1
    for (int tk2 = 0; tk2 < 64; ++tk2) {
        if (!flagsL[tk2]) continue;                  // uniform branch (LDS)
        rstage[tid] = rs[(size_t)tid * T + tk2];     // tid == d, D == 256
        __syncthreads();
        const float thr = g1L[tk2] + 0.0065f;
        double bb2 = 1e300; int bbi = 0x7fffffff;
        #pragma unroll 1
        for (int jj = 0; jj < 4; ++jj) {
            const int bin = tid + 256 * jj;          // ascending -> lowest-idx kept
            const float* crow = cbq + (size_t)bin * D;
            float f0 = 0.f, f1 = 0.f, f2 = 0.f, f3 = 0.f;
            for (int d = 0; d < D; d += 4) {
                const float4 rv = *(const float4*)&rstage[d];
                const float4 cv = *(const float4*)&crow[d];
                f0 = fmaf(rv.x, cv.x, f0); f1 = fmaf(rv.y, cv.y, f1);
                f2 = fmaf(rv.z, cv.z, f2); f3 = fmaf(rv.w, cv.w, f3);
            }
            const float sf = fmaf(-2.0f, (f0 + f1) + (f2 + f3), normsp[bin]);
            if (sf <= thr) {                         // rare: ~1-3 bins per token
                double a = 0.0;
                for (int d = 0; d < D; d += 4) {
                    const float4 rv = *(const float4*)&rstage[d];
                    const float4 cv = *(const float4*)&crow[d];
                    a = fma((double)rv.x, (double)cv.x, a);
                    a = fma((double)rv.y, (double)cv.y, a);
                    a = fma((double)rv.z, (double)cv.z, a);
                    a = fma((double)rv.w, (double)cv.w, a);
                }
                const double s = fma(-2.0, a, cbn[q * BINS + bin]);
                if (s < bb2) { bb2 = s; bbi = bin; }
            }
        }
        #pragma unroll
        for (int off = 32; off >= 1; off >>= 1) {
            const double ov = __shfl_xor(bb2, off, 64);
            const int   oi  = __shfl_xor(bbi, off, 64);
            if (ov < bb2 || (ov == bb2 && oi < bbi)) { bb2 = ov; bbi = oi; }
        }
        if (lane == 0) { redw[w] = bb2; rediw[w] = bbi; }
        __syncthreads();
        if (tid == 0) {
            double mv = redw[0]; int mi = rediw[0];
            #pragma unroll
            for (int wv = 1; wv < 4; ++wv) {
                const double ov = redw[wv]; const int oi = rediw[wv];
                if (ov < mv || (ov == mv && oi < mi)) { mv = ov; mi = oi; }
            }
            idxsL[tk2] = mi;
        }
        __syncthreads();
    }

    // ---- 6. codes
    if (tid < 64)
        out[OFF_C + (size_t)q * B * T + (size_t)b * T + t0 + tid] = (float)idxsL[tid];

    // ---- 7. faithful f32 straight-through update + loss, 16 tokens at a time:
    //         stage chosen codebook rows coalesced into dead BBUF (padded 257),
    //         then fully-coalesced update (no scattered gathers).
    float* rows = resf;   // [16][257]
    double lacc = 0.0;
    #pragma unroll 1
    for (int g = 0; g < 4; ++g) {
        __syncthreads();                         // prev g's reads done
        {
            const int j = tid >> 4, c = tid & 15;
            const float* crow = cbq + (size_t)idxsL[g * 16 + j] * D + c * 16;
            #pragma unroll
            for (int k2 = 0; k2 < 4; ++k2) {
                const float4 v = *(const float4*)(crow + k2 * 4);
                *(float4*)&rows[j * 257 + c * 16 + k2 * 4] = v;
            }
        }
        __syncthreads();
        #pragma unroll
        for (int it = 0; it < 16; ++it) {
            const int tk16 = tid & 15;
            const int dd_  = it * 16 + (tid >> 4);
            const int tk   = g * 16 + tk16;
            const float r  = rs[(size_t)dd_ * T + tk];
            const float cv = rows[tk16 * 257 + dd_];
            const float e   = cv - r;
            const float qst = r + e;
            const float dv  = qst - r;
            lacc = fma((double)dv, (double)dv, lacc);
            rd[(size_t)dd_ * T + tk] = r - qst;
        }
    }

    // ---- 8. deterministic per-block loss partial (wave shuffle + tiny LDS)
    #pragma unroll
    for (int off = 32; off >= 1; off >>= 1)
        lacc += __shfl_xor(lacc, off, 64);
    __syncthreads();
    if (lane == 0) redw[w] = lacc;
    __syncthreads();
    if (tid == 0)
        lpart[(size_t)q * 1024 + bid] = (redw[0] + redw[1]) + (redw[2] + redw[3]);
}

// ---------------- final: quantized = x - res, in place on out[0:B*D*T) ----------
__global__ __launch_bounds__(256) void final_sub(const float* __restrict__ x,
                                                 float* __restrict__ o)
{
    const size_t i = ((size_t)blockIdx.x * 256 + threadIdx.x) * 4;
    const float4v xv = __builtin_nontemporal_load((const float4v*)(x + i));
    const float4v ov = __builtin_nontemporal_load((const float4v*)(o + i));
    const float4v r = xv - ov;
    __builtin_nontemporal_store(r, (float4v*)(o + i));
}

// ---------------- OLD PATH (R2, known-good) kept as ws-size fallback ----------------
#define OTOK 32
#define ORS 260
__global__ __launch_bounds__(256, 3) void rvq_main_old(
    const float* __restrict__ x, const float* __restrict__ cb,
    const double* __restrict__ cbn, const float* __restrict__ cbnf,
    float* __restrict__ out, double* __restrict__ lpart)
{
    __shared__ float  res[OTOK][ORS];
    __shared__ float  bv1s[OTOK][16];
    __shared__ float  bv2s[OTOK][16];
    __shared__ int    bi1s[OTOK][16];
    __shared__ int    idxs[OTOK];
    __shared__ int    flags[OTOK];
    __shared__ double fbv[256];
    __shared__ int    fbi[256];

    const int tid = threadIdx.x;
    const int bid = blockIdx.x;
    const int b  = bid >> 7;
    const int t0 = (bid & 127) * OTOK;

    const float* xb = x + (size_t)b * D * T + t0;
    #pragma unroll
    for (int it = 0; it < 32; ++it) {
        const int d  = it * 8 + (tid >> 5);
        const int tk = tid & 31;
        res[tk][d] = xb[(size_t)d * T + tk];
    }
    __syncthreads();

    float qreg[32];
    #pragma unroll
    for (int i = 0; i < 32; ++i) qreg[i] = 0.0f;

    const int tg = tid & 15;
    const int bg = tid >> 4;
    const int tku = tid >> 3;
    const int d0u = (tid & 7) * 32;
    double lacc = 0.0;

    for (int q = 0; q < NQ; ++q) {
        const float*  cbq = cb   + (size_t)q * BINS * D;
        const float*  cnf = cbnf + (size_t)q * BINS;
        const double* cnd = cbn  + (size_t)q * BINS;

        float bvA = 3.4e38f, bvA2 = 3.4e38f;  int biA = 0;
        float bvB = 3.4e38f, bvB2 = 3.4e38f;  int biB = 0;

        for (int iter = 0; iter < 8; ++iter) {
            const int binbase = iter * 128 + bg * 8;
            float a0[8], a1[8];
            #pragma unroll
            for (int j = 0; j < 8; ++j) { a0[j] = 0.0f; a1[j] = 0.0f; }
            for (int d = 0; d < D; d += 4) {
                const float4 r0 = *(const float4*)&res[tg][d];
                const float4 r1 = *(const float4*)&res[tg + 16][d];
                #pragma unroll
                for (int j = 0; j < 8; ++j) {
                    const float4 c = *(const float4*)&cbq[(size_t)(binbase + j) * D + d];
                    a0[j] = fmaf(r0.x, c.x, a0[j]); a0[j] = fmaf(r0.y, c.y, a0[j]);
                    a0[j] = fmaf(r0.z, c.z, a0[j]); a0[j] = fmaf(r0.w, c.w, a0[j]);
                    a1[j] = fmaf(r1.x, c.x, a1[j]); a1[j] = fmaf(r1.y, c.y, a1[j]);
                    a1[j] = fmaf(r1.z, c.z, a1[j]); a1[j] = fmaf(r1.w, c.w, a1[j]);
                }
            }
            #pragma unroll
            for (int j = 0; j < 8; ++j) {
                const int bin = binbase + j;
                const float qn = cnf[bin];
                const float s0 = fmaf(-2.0f, a0[j], qn);
                const float s1 = fmaf(-2.0f, a1[j], qn);
                if (s0 < bvA) { bvA2 = bvA; bvA = s0; biA = bin; }
                else if (s0 < bvA2) { bvA2 = s0; }
                if (s1 < bvB) { bvB2 = bvB; bvB = s1; biB = bin; }
                else if (s1 < bvB2) { bvB2 = s1; }
            }
        }
        bv1s[tg][bg]      = bvA;  bv2s[tg][bg]      = bvA2;  bi1s[tg][bg]      = biA;
        bv1s[tg + 16][bg] = bvB;  bv2s[tg + 16][bg] = bvB2;  bi1s[tg + 16][bg] = biB;
        __syncthreads();

        if (tid < OTOK) {
            float g1 = bv1s[tid][0], g2 = bv2s[tid][0];
            int   gi = bi1s[tid][0];
            #pragma unroll
            for (int g = 1; g < 16; ++g) {
                const float v1 = bv1s[tid][g];
                const float v2 = bv2s[tid][g];
                const int   i1 = bi1s[tid][g];
                if (v1 < g1 || (v1 == g1 && i1 < gi)) { g2 = fminf(g1, v2); g1 = v1; gi = i1; }
                else g2 = fminf(g2, v1);
            }
            idxs[tid]  = gi;
            flags[tid] = (g2 - g1 < 0.02f) ? 1 : 0;
        }
        __syncthreads();

        for (int tok = 0; tok < OTOK; ++tok) {
            if (!flags[tok]) continue;
            double bb = 1e300; int bbi = 0;
            #pragma unroll
            for (int jj = 0; jj < 4; ++jj) {
                const int bin = tid + 256 * jj;
                const float* crow = cbq + (size_t)bin * D;
                double a = 0.0;
                for (int d = 0; d < D; d += 4) {
                    const float4 r = *(const float4*)&res[tok][d];
                    const float4 c = *(const float4*)&crow[d];
                    a = fma((double)r.x, (double)c.x, a);
                    a = fma((double)r.y, (double)c.y, a);
                    a = fma((double)r.z, (double)c.z, a);
                    a = fma((double)r.w, (double)c.w, a);
                }
                const double s = fma(-2.0, a, cnd[bin]);
                if (s < bb) { bb = s; bbi = bin; }
            }
            fbv[tid] = bb; fbi[tid] = bbi;
            __syncthreads();
            for (int s2 = 128; s2 >= 1; s2 >>= 1) {
                if (tid < s2) {
                    const double ov = fbv[tid + s2]; const int oi = fbi[tid + s2];
                    const double mv = fbv[tid];      const int mi = fbi[tid];
                    if (ov < mv || (ov == mv && oi < mi)) { fbv[tid] = ov; fbi[tid] = oi; }
                }
                __syncthreads();
            }
            if (tid == 0) idxs[tok] = fbi[0];
            __syncthreads();
        }

        if (tid < OTOK)
            out[OFF_C + (size_t)q * B * T + (size_t)b * T + t0 + tid] = (float)idxs[tid];

        const float* crow = cbq + (size_t)idxs[tku] * D;
        #pragma unroll
        for (int i = 0; i < 8; ++i) {
            const int d = d0u + i * 4;
            const float4 qv = *(const float4*)&crow[d];
            float4 r = *(float4*)&res[tku][d];
            float e, qst, dd;
            e = qv.x - r.x; qst = r.x + e; dd = qst - r.x;
            lacc = fma((double)dd, (double)dd, lacc); qreg[i*4+0] += qst; r.x = r.x - qst;
            e = qv.y - r.y; qst = r.y + e; dd = qst - r.y;
            lacc = fma((double)dd, (double)dd, lacc); qreg[i*4+1] += qst; r.y = r.y - qst;
            e = qv.z - r.z; qst = r.z + e; dd = qst - r.z;
            lacc = fma((double)dd, (double)dd, lacc); qreg[i*4+2] += qst; r.z = r.z - qst;
            e = qv.w - r.w; qst = r.w + e; dd = qst - r.w;
            lacc = fma((double)dd, (double)dd, lacc); qreg[i*4+3] += qst; r.w = r.w - qst;
            *(float4*)&res[tku][d] = r;
        }
        __syncthreads();
    }

    #pragma unroll
    for (int i = 0; i < 8; ++i)
        *(float4*)&res[tku][d0u + i * 4] = *(float4*)&qreg[i * 4];
    __syncthreads();
    #pragma unroll
    for (int it = 0; it < 32; ++it) {
        const int d  = it * 8 + (tid >> 5);
        const int tk = tid & 31;
        out[(size_t)b * D * T + (size_t)d * T + t0 + tk] = res[tk][d];
    }

    fbv[tid] = lacc;
    __syncthreads();
    for (int s2 = 128; s2 >= 1; s2 >>= 1) {
        if (tid < s2) fbv[tid] += fbv[tid + s2];
        __syncthreads();
    }
    if (tid == 0) lpart[bid] = fbv[0];
}

// ---------------- finalize: loss mean + bandwidth scalar ----------------
__global__ __launch_bounds__(256) void finalize_kernel(
    const double* __restrict__ lpart, int nblk,
    const int* __restrict__ srp, float* __restrict__ out)
{
    __shared__ double sh[256];
    double a = 0.0;
    for (int i = threadIdx.x; i < nblk; i += 256) a += lpart[i];
    sh[threadIdx.x] = a;
    __syncthreads();
    for (int s = 128; s >= 1; s >>= 1) {
        if (threadIdx.x < s) sh[threadIdx.x] += sh[threadIdx.x + s];
        __syncthreads();
    }
    if (threadIdx.x == 0) {
        out[OFF_L]  = (float)(sh[0] / ((double)NQ * B * T * D));
        out[OFF_BW] = (float)((double)NQ * 10.0 * (double)srp[0] / 1000.0);
    }
}

extern "C" void kernel_launch(void* const* d_in, const int* in_sizes, int n_in,
                              void* d_out, int out_size, void* d_ws, size_t ws_size,
                              hipStream_t stream)
{
    const float* x  = (const float*)d_in[0];
    const float* cb = (const float*)d_in[1];
    const int*   sr = (const int*)d_in[2];
    float* out = (float*)d_out;

    // ws layout: cbn f64[8192] @0 (65536) | cbnf f32[8192] @65536 (32768)
    //            lpart f64[8192] @98304 (65536) | bfh @163840 (4 MiB) | bfl @4358144
    //            total 8552448 B
    double* cbn   = (double*)d_ws;
    float*  cbnf  = (float*)((char*)d_ws + 65536);
    double* lpart = (double*)((char*)d_ws + 98304);
    unsigned short* bfh = (unsigned short*)((char*)d_ws + 163840);
    unsigned short* bfl = (unsigned short*)((char*)d_ws + 4358144);

    hipLaunchKernelGGL(cbnorm_kernel, dim3(NQ * BINS / 4), dim3(256), 0, stream, cb, cbn, cbnf);

    if (ws_size >= (size_t)8552448) {
        hipLaunchKernelGGL(prep_bfrag, dim3(1024), dim3(256), 0, stream, cb, bfh, bfl);
        float* resb = out;   // quantized section doubles as residual buffer
        for (int q = 0; q < NQ; ++q) {
            hipLaunchKernelGGL(rvq_scan, dim3(B * (T / 64)), dim3(256), 0, stream,
                               (q == 0 ? x : (const float*)resb), resb, cb, cbn, cbnf,
                               bfh, bfl, out, lpart, q);
        }
        hipLaunchKernelGGL(final_sub, dim3((B * D * T) / 1024), dim3(256), 0, stream, x, resb);
        hipLaunchKernelGGL(finalize_kernel, dim3(1), dim3(256), 0, stream,
                           lpart, NQ * 1024, sr, out);
    } else {
        hipLaunchKernelGGL(rvq_main_old, dim3(B * (T / OTOK)), dim3(256), 0, stream,
                           x, cb, cbn, cbnf, out, lpart);
        hipLaunchKernelGGL(finalize_kernel, dim3(1), dim3(256), 0, stream,
                           lpart, B * (T / OTOK), sr, out);
    }
}